// Round 1
// baseline (483.318 us; speedup 1.0000x reference)
//
#include <hip/hip_runtime.h>
#include <hip/hip_fp16.h>
#include <math.h>

// 2-layer GAT. f16 MFMA GEMMs (fused attention-scalar B-tiles, fused fp32->f16
// A-convert), fp8-e4m3 feature storage for the edge gathers, single-pass
// segment softmax, fp32 accumulation. Aggregations use a statically-unrolled
// 4-stage pipeline: cs/aj ring 16 edges ahead, feature gather prefetched 8
// edges ahead via a cs register loaded 2 stages prior (no dependent stall,
// no runtime-indexed register arrays — R11 lesson).
//
// CSR build (R12): device-scope atomics forwarded past L2 at ~22 G/s were the
// bottleneck (k_rank: VALU 0.4%, WRITE_SIZE = E*32B atomic packets). Replaced
// by XCD-LOCAL atomics: nodes are partitioned by owner(d)=(d>>11)&7 (8KB-
// aligned stripes), each block reads its physical XCD id (s_getreg XCC_ID,
// HW-verified 0..7 on MI355X) and pulls edge chunks from a per-XCD queue, so
// every deg/cursor line is only ever atomiced from ONE XCD -> workgroup-scope
// atomics execute in that XCD's own L2 (no sc1, no fabric round-trip).
// Coverage safety: if an XCD gets zero blocks its queue counter stays 0 and
// its partitions saw ZERO local atomics; a fix kernel then handles exactly
// those partitions with device-scope atomics (scope mixing safe because the
// orphaned lines were never locally atomiced). Also deletes the rank array:
// the fill pass gets slots straight from cursor fetch_add.

typedef _Float16 f16x8 __attribute__((ext_vector_type(8)));   // 8 f16 (4 VGPRs)
typedef float f32x4 __attribute__((ext_vector_type(4)));
typedef float f32x2 __attribute__((ext_vector_type(2)));

__device__ __forceinline__ float lrelu02(float x){ return x > 0.f ? x : 0.2f*x; }
__device__ __forceinline__ unsigned char f2fp8(float v){
  return (unsigned char)(__builtin_amdgcn_cvt_pk_fp8_f32(v, v, 0, false) & 0xff);
}

// HW_REG_XCC_ID: id=20, offset=0, size=4  ->  imm = 20 | ((4-1)<<11)
#define HWREG_XCC_ID (20 | (3 << 11))
#define OWNER(d) (((d) >> 11) & 7)
#define CSR_CHUNK 4096

// ---------------- graph build: XCD-local histogram ----------------
__global__ __launch_bounds__(256) void k_hist(const int* __restrict__ dst,
    int* __restrict__ deg, int* __restrict__ q, int E, int nchunk){
  __shared__ int sc;
  int xcd = (int)(__builtin_amdgcn_s_getreg(HWREG_XCC_ID) & 7);
  int tid = threadIdx.x;
  for (;;){
    if (tid == 0) sc = atomicAdd(&q[xcd], 1);   // device-scope: 8 counters, trivial
    __syncthreads();
    int c = sc;
    __syncthreads();
    if (c >= nchunk) return;
    int lo = c*CSR_CHUNK, hi = min(lo + CSR_CHUNK, E);
    if (hi == lo + CSR_CHUNK){
      #pragma unroll
      for (int k = 0; k < CSR_CHUNK/256; ++k){
        int d = dst[lo + tid + k*256];
        if (OWNER(d) == xcd)
          __hip_atomic_fetch_add(&deg[d], 1, __ATOMIC_RELAXED, __HIP_MEMORY_SCOPE_WORKGROUP);
      }
    } else {
      for (int i = lo + tid; i < hi; i += 256){
        int d = dst[i];
        if (OWNER(d) == xcd)
          __hip_atomic_fetch_add(&deg[d], 1, __ATOMIC_RELAXED, __HIP_MEMORY_SCOPE_WORKGROUP);
      }
    }
  }
}

// Fallback: partitions whose XCD got no blocks (q[x]==0) saw zero local
// atomics -> finish them with device-scope atomics. Normally early-exits.
__global__ void k_hist_fix(const int* __restrict__ dst, const int* __restrict__ q,
                           int* __restrict__ deg, int E){
  int mask = 0;
  #pragma unroll
  for (int x = 0; x < 8; ++x) mask |= (q[x] == 0) << x;
  if (!mask) return;
  int stride = gridDim.x*blockDim.x;
  for (int i = blockIdx.x*blockDim.x + threadIdx.x; i < E; i += stride){
    int d = dst[i];
    if ((mask >> OWNER(d)) & 1) atomicAdd(&deg[d], 1);
  }
}

__global__ void k_scanA(const int* __restrict__ deg, int* __restrict__ rowstart,
                        int* __restrict__ bsum, int N){
  __shared__ int lds[256];
  int t = threadIdx.x;
  int base = blockIdx.x*1024 + t*4;
  int v0 = (base+0<N)?deg[base+0]:0;
  int v1 = (base+1<N)?deg[base+1]:0;
  int v2 = (base+2<N)?deg[base+2]:0;
  int v3 = (base+3<N)?deg[base+3]:0;
  lds[t] = v0+v1+v2+v3;
  __syncthreads();
  for (int off=1; off<256; off<<=1){
    int x = (t>=off)? lds[t-off] : 0;
    __syncthreads();
    lds[t] += x;
    __syncthreads();
  }
  int run = (t==0)? 0 : lds[t-1];
  if (base+0<N) rowstart[base+0]=run;
  run += v0;
  if (base+1<N) rowstart[base+1]=run;
  run += v1;
  if (base+2<N) rowstart[base+2]=run;
  run += v2;
  if (base+3<N) rowstart[base+3]=run;
  if (t==255) bsum[blockIdx.x] = lds[255];
}

__global__ void k_scanB(int* bsum, int nblk){
  __shared__ int lds[128];
  int t = threadIdx.x;
  lds[t] = (t<nblk)? bsum[t] : 0;
  __syncthreads();
  for (int off=1; off<128; off<<=1){
    int x = (t>=off)? lds[t-off] : 0;
    __syncthreads();
    lds[t] += x;
    __syncthreads();
  }
  if (t<nblk) bsum[t] = (t==0)? 0 : lds[t-1];
}

__global__ void k_scanC(int* rowstart, int* __restrict__ cursor,
                        const int* __restrict__ bsum, int N, int E){
  int i = blockIdx.x*blockDim.x + threadIdx.x;
  if (i < N){
    int v = rowstart[i] + bsum[i>>10];
    rowstart[i] = v;
    cursor[i] = v;
  }
  if (i == 0) rowstart[N] = E;
}

// ---------------- graph build: XCD-local CSR fill (replaces rank+fillx) ----------------
__global__ __launch_bounds__(256) void k_fill(const int* __restrict__ src,
    const int* __restrict__ dst, int* __restrict__ cursor, int* __restrict__ csr,
    int* __restrict__ q, int E, int nchunk){
  __shared__ int sc;
  int xcd = (int)(__builtin_amdgcn_s_getreg(HWREG_XCC_ID) & 7);
  int tid = threadIdx.x;
  for (;;){
    if (tid == 0) sc = atomicAdd(&q[xcd], 1);
    __syncthreads();
    int c = sc;
    __syncthreads();
    if (c >= nchunk) return;
    int lo = c*CSR_CHUNK, hi = min(lo + CSR_CHUNK, E);
    if (hi == lo + CSR_CHUNK){
      #pragma unroll
      for (int k = 0; k < CSR_CHUNK/256; ++k){
        int i = lo + tid + k*256;
        int d = dst[i];
        if (OWNER(d) == xcd){
          int slot = __hip_atomic_fetch_add(&cursor[d], 1, __ATOMIC_RELAXED, __HIP_MEMORY_SCOPE_WORKGROUP);
          csr[slot] = src[i];
        }
      }
    } else {
      for (int i = lo + tid; i < hi; i += 256){
        int d = dst[i];
        if (OWNER(d) == xcd){
          int slot = __hip_atomic_fetch_add(&cursor[d], 1, __ATOMIC_RELAXED, __HIP_MEMORY_SCOPE_WORKGROUP);
          csr[slot] = src[i];
        }
      }
    }
  }
}

__global__ void k_fill_fix(const int* __restrict__ src, const int* __restrict__ dst,
                           const int* __restrict__ q, int* __restrict__ cursor,
                           int* __restrict__ csr, int E){
  int mask = 0;
  #pragma unroll
  for (int x = 0; x < 8; ++x) mask |= (q[x] == 0) << x;
  if (!mask) return;
  int stride = gridDim.x*blockDim.x;
  for (int i = blockIdx.x*blockDim.x + threadIdx.x; i < E; i += stride){
    int d = dst[i];
    if ((mask >> OWNER(d)) & 1){
      int slot = atomicAdd(&cursor[d], 1);
      csr[slot] = src[i];
    }
  }
}

// ---------------- weight prep: f16 weights + att-folded tiles + bias consts ----------------
__global__ void k_prep(const float* __restrict__ W1, const float* __restrict__ b1,
                       const float* __restrict__ att1,
                       const float* __restrict__ W2, const float* __restrict__ b2,
                       const float* __restrict__ att2,
                       _Float16* __restrict__ W1h, _Float16* __restrict__ W2h,
                       _Float16* __restrict__ attB1, _Float16* __restrict__ attB2,
                       float* __restrict__ consts){
  int i = blockIdx.x*blockDim.x + threadIdx.x;
  if (i < 16384){ W1h[i] = (_Float16)W1[i]; return; }
  i -= 16384;
  if (i < 6144){ int r = i >> 7; W2h[i] = (r < 40)? (_Float16)W2[i] : (_Float16)0.f; return; }
  i -= 6144;
  if (i < 2048){
    int j = i >> 7, k = i & 127;
    int h = j & 7, half = (j >> 3)*16;
    float s = 0.f;
    for (int c = 0; c < 16; ++c) s += att1[h*32 + half + c]*W1[(h*16+c)*128 + k];
    attB1[i] = (_Float16)s; return;
  }
  i -= 2048;
  if (i < 2048){
    int j = i >> 7, k = i & 127;
    float s = 0.f;
    if (j < 2){ const float* av = att2 + j*40; for (int c = 0; c < 40; ++c) s += av[c]*W2[c*128 + k]; }
    attB2[i] = (_Float16)s; return;
  }
  i -= 2048;
  if (i < 18){
    float s = 0.f;
    if (i < 8){ for (int c = 0; c < 16; ++c) s += b1[i*16+c]*att1[i*32+c]; }
    else if (i < 16){ int h = i-8; for (int c = 0; c < 16; ++c) s += b1[h*16+c]*att1[h*32+16+c]; }
    else if (i == 16){ for (int c = 0; c < 40; ++c) s += b2[c]*att2[c]; }
    else { for (int c = 0; c < 40; ++c) s += b2[c]*att2[40+c]; }
    consts[i] = s;
  }
}

// ---------------- GEMM1 (MFMA f16): h1 (fp8, row-major) + a1i/a1j (fp32) ----------------
__global__ __launch_bounds__(256) void k_gemm1(const float* __restrict__ x,
    const _Float16* __restrict__ Wh, const _Float16* __restrict__ attB,
    const float* __restrict__ b1, const float* __restrict__ consts,
    unsigned char* __restrict__ h1f8, float* __restrict__ a1i, float* __restrict__ a1j, int N){
  int wid  = (blockIdx.x*256 + threadIdx.x) >> 6;
  int lane = threadIdx.x & 63;
  int m0 = wid*16;
  if (m0 >= N) return;
  int col = lane & 15, quad = lane >> 4;
  const float* xr = x + (size_t)(m0+col)*128 + quad*8;
  f32x4 acc[9];
  #pragma unroll
  for (int t=0;t<9;t++){ acc[t][0]=0.f; acc[t][1]=0.f; acc[t][2]=0.f; acc[t][3]=0.f; }
  #pragma unroll
  for (int q=0;q<4;q++){
    float4 f0 = ((const float4*)(xr + q*32))[0];
    float4 f1 = ((const float4*)(xr + q*32))[1];
    f16x8 a;
    a[0]=(_Float16)f0.x; a[1]=(_Float16)f0.y; a[2]=(_Float16)f0.z; a[3]=(_Float16)f0.w;
    a[4]=(_Float16)f1.x; a[5]=(_Float16)f1.y; a[6]=(_Float16)f1.z; a[7]=(_Float16)f1.w;
    #pragma unroll
    for (int t=0;t<8;t++){
      const f16x8* Bp = (const f16x8*)(Wh + (size_t)(t*16+col)*128 + q*32 + quad*8);
      acc[t] = __builtin_amdgcn_mfma_f32_16x16x32_f16(a, *Bp, acc[t], 0,0,0);
    }
    const f16x8* Ap = (const f16x8*)(attB + (size_t)col*128 + q*32 + quad*8);
    acc[8] = __builtin_amdgcn_mfma_f32_16x16x32_f16(a, *Ap, acc[8], 0,0,0);
  }
  #pragma unroll
  for (int t=0;t<8;t++){
    int c = t*16 + col;
    float bb = b1[c];
    #pragma unroll
    for (int r=0;r<4;r++){
      h1f8[(size_t)(m0 + quad*4 + r)*128 + c] = f2fp8(acc[t][r] + bb);
    }
  }
  float hb = consts[col];
  #pragma unroll
  for (int r=0;r<4;r++){
    int node = m0 + quad*4 + r;
    float v = acc[8][r] + hb;
    if (col < 8) a1i[node*8 + col] = v;
    else         a1j[node*8 + (col-8)] = v;
  }
}

// ---------------- layer-1 fused softmax+aggregate: 4-stage pipelined fp8 gather ----------------
// one wave per node; quarter qt owns edge e+qt of each group of 4; lane ql owns
// channels 8*ql..8*ql+7 (uint2 of fp8), head = ql>>1. cs/aj ring: 16 edges ahead;
// feature u: 8 edges ahead via cs loaded 2 stages prior. fp32 accumulation.
__global__ __launch_bounds__(256) void k_agg1(const uint2* __restrict__ h1q,
    const float* __restrict__ a1i, const float* __restrict__ a1j,
    const int* __restrict__ rowstart, const int* __restrict__ csr,
    const float* __restrict__ bias, uint4* __restrict__ x2u4, int N){
  int lane = threadIdx.x & 63;
  int n = (blockIdx.x*blockDim.x + threadIdx.x) >> 6;
  if (n >= N) return;
  int ql = lane & 15, qt = lane >> 4;
  unsigned hd = (unsigned)ql >> 1;
  int rs = rowstart[n], re = rowstart[n+1];
  float ai2 = a1i[(unsigned)n*8u + hd];
  float a0=0.f,a1=0.f,a2=0.f,a3=0.f,a4=0.f,a5=0.f,a6=0.f,a7=0.f,den=0.f;
  {
    float w = (qt==0)? __expf(lrelu02(ai2 + a1j[(unsigned)n*8u + hd])) : 0.f;
    uint2 u = h1q[(unsigned)n*16u + (unsigned)ql];
    f32x2 f0 = __builtin_amdgcn_cvt_pk_f32_fp8((int)u.x, false);
    f32x2 f1 = __builtin_amdgcn_cvt_pk_f32_fp8((int)u.x, true);
    f32x2 f2 = __builtin_amdgcn_cvt_pk_f32_fp8((int)u.y, false);
    f32x2 f3 = __builtin_amdgcn_cvt_pk_f32_fp8((int)u.y, true);
    a0=w*f0[0]; a1=w*f0[1]; a2=w*f1[0]; a3=w*f1[1];
    a4=w*f2[0]; a5=w*f2[1]; a6=w*f3[0]; a7=w*f3[1];
    den = w;
  }
  int last = re - 1;
  if (rs < re){
    unsigned cs0 = (unsigned)csr[min(rs+0+qt,last)];
    unsigned cs1 = (unsigned)csr[min(rs+4+qt,last)];
    unsigned cs2 = (unsigned)csr[min(rs+8+qt,last)];
    unsigned cs3 = (unsigned)csr[min(rs+12+qt,last)];
    float aj0 = a1j[cs0*8u+hd], aj1 = a1j[cs1*8u+hd];
    float aj2 = a1j[cs2*8u+hd], aj3 = a1j[cs3*8u+hd];
    uint2 ua = h1q[(size_t)cs0*16u + (unsigned)ql];
    uint2 ub = h1q[(size_t)cs1*16u + (unsigned)ql];
    int e0 = rs;

#define AGG1_STAGE(AJ, CSPRE, CSSLOT, OFF)                                   \
    {                                                                        \
      uint2 uc = h1q[(size_t)CSPRE*16u + (unsigned)ql];                      \
      unsigned nc = (unsigned)csr[min(e0+OFF+16+qt, last)];                  \
      float w = (e0+OFF+qt < re)? __expf(lrelu02(ai2 + AJ)) : 0.f;           \
      den += w;                                                              \
      f32x2 g0 = __builtin_amdgcn_cvt_pk_f32_fp8((int)ua.x, false);          \
      f32x2 g1 = __builtin_amdgcn_cvt_pk_f32_fp8((int)ua.x, true);           \
      f32x2 g2 = __builtin_amdgcn_cvt_pk_f32_fp8((int)ua.y, false);          \
      f32x2 g3 = __builtin_amdgcn_cvt_pk_f32_fp8((int)ua.y, true);           \
      a0 += w*g0[0]; a1 += w*g0[1]; a2 += w*g1[0]; a3 += w*g1[1];            \
      a4 += w*g2[0]; a5 += w*g2[1]; a6 += w*g3[0]; a7 += w*g3[1];            \
      CSSLOT = nc; AJ = a1j[nc*8u + hd];                                     \
      ua = ub; ub = uc;                                                      \
    }

    while (e0 < re){
      AGG1_STAGE(aj0, cs2, cs0, 0)
      if (e0+4 >= re) break;
      AGG1_STAGE(aj1, cs3, cs1, 4)
      if (e0+8 >= re) break;
      AGG1_STAGE(aj2, cs0, cs2, 8)
      if (e0+12 >= re) break;
      AGG1_STAGE(aj3, cs1, cs3, 12)
      e0 += 16;
    }
#undef AGG1_STAGE
  }
  #pragma unroll
  for (int off = 16; off < 64; off <<= 1){
    den += __shfl_xor(den, off);
    a0 += __shfl_xor(a0, off); a1 += __shfl_xor(a1, off);
    a2 += __shfl_xor(a2, off); a3 += __shfl_xor(a3, off);
    a4 += __shfl_xor(a4, off); a5 += __shfl_xor(a5, off);
    a6 += __shfl_xor(a6, off); a7 += __shfl_xor(a7, off);
  }
  if (qt == 0){
    float invd = 1.f/(den + 1e-16f);
    const float4* b4 = (const float4*)(bias + 8*ql);
    float4 bl = b4[0], bh = b4[1];
    float o0=a0*invd+bl.x, o1=a1*invd+bl.y, o2=a2*invd+bl.z, o3=a3*invd+bl.w;
    float o4=a4*invd+bh.x, o5=a5*invd+bh.y, o6=a6*invd+bh.z, o7=a7*invd+bh.w;
    o0=(o0>0.f)?o0:(__expf(o0)-1.f); o1=(o1>0.f)?o1:(__expf(o1)-1.f);
    o2=(o2>0.f)?o2:(__expf(o2)-1.f); o3=(o3>0.f)?o3:(__expf(o3)-1.f);
    o4=(o4>0.f)?o4:(__expf(o4)-1.f); o5=(o5>0.f)?o5:(__expf(o5)-1.f);
    o6=(o6>0.f)?o6:(__expf(o6)-1.f); o7=(o7>0.f)?o7:(__expf(o7)-1.f);
    __half2 p0 = __floats2half2_rn(o0,o1), p1 = __floats2half2_rn(o2,o3);
    __half2 p2 = __floats2half2_rn(o4,o5), p3 = __floats2half2_rn(o6,o7);
    uint4 o;
    o.x = *(unsigned*)&p0; o.y = *(unsigned*)&p1; o.z = *(unsigned*)&p2; o.w = *(unsigned*)&p3;
    x2u4[(unsigned)n*16u + (unsigned)ql] = o;   // x2 stays f16 (MFMA A operand)
  }
}

// ---------------- GEMM2 (MFMA f16): h2 (fp8) + a2i/a2j ----------------
__global__ __launch_bounds__(256) void k_gemm2(const _Float16* __restrict__ xh,
    const _Float16* __restrict__ Wh, const _Float16* __restrict__ attB,
    const float* __restrict__ b2, const float* __restrict__ consts,
    unsigned char* __restrict__ h2f8, float* __restrict__ a2i, float* __restrict__ a2j, int N){
  int wid  = (blockIdx.x*256 + threadIdx.x) >> 6;
  int lane = threadIdx.x & 63;
  int m0 = wid*16;
  if (m0 >= N) return;
  int col = lane & 15, quad = lane >> 4;
  const f16x8* A8 = (const f16x8*)(xh + (size_t)(m0+col)*128 + quad*8);
  f32x4 acc[4];
  #pragma unroll
  for (int t=0;t<4;t++){ acc[t][0]=0.f; acc[t][1]=0.f; acc[t][2]=0.f; acc[t][3]=0.f; }
  #pragma unroll
  for (int q=0;q<4;q++){
    f16x8 a = A8[q*4];
    #pragma unroll
    for (int t=0;t<3;t++){
      const f16x8* Bp = (const f16x8*)(Wh + (size_t)(t*16+col)*128 + q*32 + quad*8);
      acc[t] = __builtin_amdgcn_mfma_f32_16x16x32_f16(a, *Bp, acc[t], 0,0,0);
    }
    const f16x8* Bp2 = (const f16x8*)(attB + (size_t)col*128 + q*32 + quad*8);
    acc[3] = __builtin_amdgcn_mfma_f32_16x16x32_f16(a, *Bp2, acc[3], 0,0,0);
  }
  #pragma unroll
  for (int t=0;t<3;t++){
    int c = t*16 + col;
    if (c < 40){
      float bb = b2[c];
      #pragma unroll
      for (int r=0;r<4;r++){
        h2f8[(size_t)(m0 + quad*4 + r)*40 + c] = f2fp8(acc[t][r] + bb);
      }
    }
  }
  if (col < 2){
    float cc = consts[16 + col];
    #pragma unroll
    for (int r=0;r<4;r++){
      int node = m0 + quad*4 + r;
      if (col == 0) a2i[node] = acc[3][r] + cc;
      else          a2j[node] = acc[3][r] + cc;
    }
  }
}

// ---------------- layer-2 fused softmax+aggregate + log_softmax ----------------
// FOUR nodes per wave (quarters); lanes ql<10 own 4 channels (uint of fp8).
// Per-quarter divergent edge loop, 4-stage pipeline: cs/aj ring 4 ahead,
// feature u prefetched 2 stages ahead. fp32 accumulation.
__global__ __launch_bounds__(256) void k_agg2(const unsigned* __restrict__ h2u,
    const float* __restrict__ a2i, const float* __restrict__ a2j,
    const int* __restrict__ rowstart, const int* __restrict__ csr,
    const float* __restrict__ bias, float* __restrict__ out, int N){
  int lane = threadIdx.x & 63;
  int wid = (blockIdx.x*blockDim.x + threadIdx.x) >> 6;
  int qt = lane >> 4, ql = lane & 15;
  int n = wid*4 + qt;
  if (n >= N) return;
  bool act = ql < 10;
  unsigned cl = act ? (unsigned)ql : 0u;
  int rs = rowstart[n], re = rowstart[n+1];
  float ai = a2i[n];
  float wself = __expf(lrelu02(ai + a2j[n]));
  float a0,a1,a2,a3,den;
  {
    unsigned u = h2u[(unsigned)n*10u + cl];
    f32x2 f0 = __builtin_amdgcn_cvt_pk_f32_fp8((int)u, false);
    f32x2 f1 = __builtin_amdgcn_cvt_pk_f32_fp8((int)u, true);
    a0 = wself*f0[0]; a1 = wself*f0[1]; a2 = wself*f1[0]; a3 = wself*f1[1];
    den = wself;
  }
  if (rs < re){
    int last = re - 1;
    unsigned cs0 = (unsigned)csr[min(rs+0,last)];
    unsigned cs1 = (unsigned)csr[min(rs+1,last)];
    unsigned cs2 = (unsigned)csr[min(rs+2,last)];
    unsigned cs3 = (unsigned)csr[min(rs+3,last)];
    float aj0 = a2j[cs0], aj1 = a2j[cs1], aj2 = a2j[cs2], aj3 = a2j[cs3];
    unsigned ua = h2u[cs0*10u + cl];
    unsigned ub = h2u[cs1*10u + cl];
    int e0 = rs;

#define AGG2_STAGE(AJ, CSPRE, CSSLOT, OFF)                                   \
    {                                                                        \
      unsigned uc = h2u[CSPRE*10u + cl];                                     \
      unsigned nc = (unsigned)csr[min(e0+OFF+4, last)];                      \
      float w = (e0+OFF < re)? __expf(lrelu02(ai + AJ)) : 0.f;               \
      den += w;                                                              \
      f32x2 g0 = __builtin_amdgcn_cvt_pk_f32_fp8((int)ua, false);            \
      f32x2 g1 = __builtin_amdgcn_cvt_pk_f32_fp8((int)ua, true);             \
      a0 += w*g0[0]; a1 += w*g0[1]; a2 += w*g1[0]; a3 += w*g1[1];            \
      CSSLOT = nc; AJ = a2j[nc];                                             \
      ua = ub; ub = uc;                                                      \
    }

    while (e0 < re){
      AGG2_STAGE(aj0, cs2, cs0, 0)
      AGG2_STAGE(aj1, cs3, cs1, 1)
      AGG2_STAGE(aj2, cs0, cs2, 2)
      AGG2_STAGE(aj3, cs1, cs3, 3)
      e0 += 4;
    }
#undef AGG2_STAGE
  }
  float invd = 1.f/(den + 1e-16f);
  const float4* b4 = (const float4*)(bias + 4*cl);
  float4 bb = b4[0];
  float v0 = a0*invd + bb.x, v1 = a1*invd + bb.y;
  float v2 = a2*invd + bb.z, v3 = a3*invd + bb.w;
  float mv = act ? fmaxf(fmaxf(v0,v1), fmaxf(v2,v3)) : -INFINITY;
  #pragma unroll
  for (int off = 1; off < 16; off <<= 1) mv = fmaxf(mv, __shfl_xor(mv, off));
  float se = act ? (__expf(v0-mv)+__expf(v1-mv)+__expf(v2-mv)+__expf(v3-mv)) : 0.f;
  #pragma unroll
  for (int off = 1; off < 16; off <<= 1) se += __shfl_xor(se, off);
  float ls = __logf(se);
  if (act){
    float4 o = make_float4(v0-mv-ls, v1-mv-ls, v2-mv-ls, v3-mv-ls);
    ((float4*)out)[(unsigned)n*10u + cl] = o;
  }
}

extern "C" void kernel_launch(void* const* d_in, const int* in_sizes, int n_in,
                              void* d_out, int out_size, void* d_ws, size_t ws_size,
                              hipStream_t stream){
  const float* x     = (const float*)d_in[0];
  const int*   ei    = (const int*)  d_in[1];
  const float* W1    = (const float*)d_in[2];
  const float* b1    = (const float*)d_in[3];
  const float* att1  = (const float*)d_in[4];
  const float* bias1 = (const float*)d_in[5];
  const float* W2    = (const float*)d_in[6];
  const float* b2    = (const float*)d_in[7];
  const float* att2  = (const float*)d_in[8];
  const float* bias2 = (const float*)d_in[9];
  int N = in_sizes[0] / 128;
  int E = in_sizes[1] / 2;
  const int* src = ei;
  const int* dst = ei + E;

  char* ws = (char*)d_ws;
  size_t off = 0;
  auto alloc = [&](size_t bytes)->char*{
    char* p = ws + off; off += (bytes + 255) & ~(size_t)255; return p;
  };
  unsigned char* h1f8 = (unsigned char*)alloc((size_t)N*128);   // fp8 row-major
  _Float16*      x2h  = (_Float16*)alloc((size_t)N*128*2);      // f16 (MFMA A)
  unsigned char* h2f8 = (unsigned char*)alloc((size_t)N*40);    // fp8 row-major
  float* a1i  = (float*)alloc((size_t)N*8*4);
  float* a1j  = (float*)alloc((size_t)N*8*4);
  float* a2i  = (float*)alloc((size_t)N*4);
  float* a2j  = (float*)alloc((size_t)N*4);
  _Float16* W1h   = (_Float16*)alloc(16384*2);
  _Float16* W2h   = (_Float16*)alloc(6144*2);
  _Float16* attB1 = (_Float16*)alloc(2048*2);
  _Float16* attB2 = (_Float16*)alloc(2048*2);
  float* consts = (float*)alloc(18*4);
  int*   deg   = (int*)  alloc((size_t)N*4);
  int*   cursor= (int*)  alloc((size_t)N*4);
  int*   rowst = (int*)  alloc((size_t)(N+1)*4);
  int*   csr   = (int*)  alloc((size_t)E*4);
  int*   bsum  = (int*)  alloc(4096);
  int*   qq    = (int*)  alloc(64);          // qq[0..7]=hist queue, qq[8..15]=fill queue

  hipMemsetAsync(deg, 0, (size_t)N*4, stream);
  hipMemsetAsync(qq, 0, 64, stream);
  int nblk = (N + 1023)/1024;
  int nchunk = (E + CSR_CHUNK - 1)/CSR_CHUNK;
  k_hist<<<1024, 256, 0, stream>>>(dst, deg, qq, E, nchunk);
  k_hist_fix<<<1024, 256, 0, stream>>>(dst, qq, deg, E);
  k_scanA<<<nblk, 256, 0, stream>>>(deg, rowst, bsum, N);
  k_scanB<<<1, 128, 0, stream>>>(bsum, nblk);
  k_scanC<<<(N+255)/256, 256, 0, stream>>>(rowst, cursor, bsum, N, E);
  k_fill<<<1024, 256, 0, stream>>>(src, dst, cursor, csr, qq+8, E, nchunk);
  k_fill_fix<<<1024, 256, 0, stream>>>(src, dst, qq+8, cursor, csr, E);
  k_prep<<<105, 256, 0, stream>>>(W1, b1, att1, W2, b2, att2, W1h, W2h, attB1, attB2, consts);

  int gblk = ((N+15)/16 + 3)/4;  // 4 waves/block, 16 nodes/wave
  k_gemm1<<<gblk, 256, 0, stream>>>(x, W1h, attB1, b1, consts, h1f8, a1i, a1j, N);
  k_agg1<<<(N*64+255)/256, 256, 0, stream>>>((const uint2*)h1f8, a1i, a1j, rowst, csr, bias1, (uint4*)x2h, N);

  k_gemm2<<<gblk, 256, 0, stream>>>(x2h, W2h, attB2, b2, consts, h2f8, a2i, a2j, N);
  k_agg2<<<(N+15)/16, 256, 0, stream>>>((const unsigned*)h2f8, a2i, a2j, rowst, csr, bias2, (float*)d_out, N);
}

// Round 2
// 322.472 us; speedup vs baseline: 1.4988x; 1.4988x over previous
//
#include <hip/hip_runtime.h>
#include <hip/hip_fp16.h>
#include <math.h>

// 2-layer GAT. f16 MFMA GEMMs (fused attention-scalar B-tiles, fused fp32->f16
// A-convert), fp8-e4m3 feature storage for the edge gathers, single-pass
// segment softmax, fp32 accumulation. Aggregations use a statically-unrolled
// 4-stage pipeline (R11 lesson: no runtime-indexed register arrays).
//
// CSR build (R13): the global-atomic wall (~22 G ops/s with-return, measured
// R0 k_rank 73us; R12 showed scope qualifiers do NOT avoid it - workgroup-
// scope atomics still emit per-edge 32B packets) is dodged by issuing FEWER
// atomics: two-level multi-split. Per 4096-edge block: LDS histogram over
// 128-node buckets (LDS atomics, CU-local), then ONE device atomicAdd per
// nonzero (block,bucket) pair (~300K total vs 1.6M), scatter edges into a
// bucket-grouped tmp (4B packed: src | (dst&127)<<17). Then one block per
// bucket: LDS 128-counter hist + scan -> writes rowstart directly (deletes
// the old deg scanA/B/C chain) and scatters csr from a contiguous, L2-hot
// bucket range. Edge order within a node becomes arbitrary (fp32 sum reorder
// only, << fp8 tolerance). tmp aliases x2h (dead until k_agg1).

typedef _Float16 f16x8 __attribute__((ext_vector_type(8)));   // 8 f16 (4 VGPRs)
typedef float f32x4 __attribute__((ext_vector_type(4)));
typedef float f32x2 __attribute__((ext_vector_type(2)));

__device__ __forceinline__ float lrelu02(float x){ return x > 0.f ? x : 0.2f*x; }
__device__ __forceinline__ unsigned char f2fp8(float v){
  return (unsigned char)(__builtin_amdgcn_cvt_pk_fp8_f32(v, v, 0, false) & 0xff);
}

#define BSHIFT 7                 // 128 nodes per bucket (N <= 131072)
#define BMASK  127
#define SPLIT_CHUNK 4096         // edges per split block

// gcur is padded: one counter per 64B line (index b*16) to spread the
// ~300K contended atomics across L3 slices.

__global__ void k_initcur(int* __restrict__ gcur, int nbucket, int cap){
  int b = blockIdx.x*blockDim.x + threadIdx.x;
  if (b < nbucket) gcur[b*16] = b*cap;
}

// ---------------- multi-split: bucket-group edges into tmp ----------------
__global__ __launch_bounds__(256) void k_split(const int* __restrict__ src,
    const int* __restrict__ dst, int* __restrict__ gcur, int* __restrict__ tmp,
    int E, int nbucket){
  __shared__ int hist[1024];
  int tid = threadIdx.x;
  for (int t = tid; t < 1024; t += 256) hist[t] = 0;
  __syncthreads();
  int lo = blockIdx.x*SPLIT_CHUNK;
  int ds[16], ss[16];
  #pragma unroll
  for (int k = 0; k < 16; ++k){
    int i = lo + tid + k*256;
    bool p = i < E;
    ds[k] = p ? dst[i] : 0;
    ss[k] = p ? src[i] : 0;
    if (p) atomicAdd(&hist[ds[k] >> BSHIFT], 1);     // LDS atomic
  }
  __syncthreads();
  // one device atomic per nonzero bucket; reuse hist[] to hold absolute base
  for (int b = tid; b < nbucket; b += 256){
    int c = hist[b];
    if (c) hist[b] = atomicAdd(&gcur[b*16], c);
  }
  __syncthreads();
  #pragma unroll
  for (int k = 0; k < 16; ++k){
    int i = lo + tid + k*256;
    if (i < E){
      int r = atomicAdd(&hist[ds[k] >> BSHIFT], 1);  // LDS atomic, abs position
      tmp[r] = ss[k] | ((ds[k] & BMASK) << 17);
    }
  }
}

// ---------------- bucket scan: counts -> bucketStart (exclusive) ----------------
__global__ void k_bscan(const int* __restrict__ gcur, int* __restrict__ bstart,
                        int* __restrict__ rowstart, int nbucket, int cap, int E, int N){
  __shared__ int lds[256];
  int t = threadIdx.x;
  int v[4]; int s = 0;
  #pragma unroll
  for (int k = 0; k < 4; ++k){
    int idx = t*4 + k;
    v[k] = (idx < nbucket) ? (gcur[idx*16] - idx*cap) : 0;
    s += v[k];
  }
  lds[t] = s;
  __syncthreads();
  for (int off = 1; off < 256; off <<= 1){
    int x = (t >= off) ? lds[t-off] : 0;
    __syncthreads();
    lds[t] += x;
    __syncthreads();
  }
  int run = (t == 0) ? 0 : lds[t-1];
  #pragma unroll
  for (int k = 0; k < 4; ++k){
    int idx = t*4 + k;
    if (idx < nbucket) bstart[idx] = run;
    run += v[k];
  }
  if (t == 0){ bstart[nbucket] = E; rowstart[N] = E; }
}

// ---------------- finalize: per-bucket node hist + scan -> rowstart + csr ----------------
__global__ __launch_bounds__(256) void k_final(const int* __restrict__ tmp,
    const int* __restrict__ gcur, const int* __restrict__ bstart,
    int* __restrict__ rowstart, int* __restrict__ csr, int cap, int N){
  __shared__ int h[128];
  __shared__ int sc[128];
  __shared__ int cur[128];
  int b = blockIdx.x;
  int tid = threadIdx.x;
  int cnt  = gcur[b*16] - b*cap;
  int base = bstart[b];
  if (tid < 128) h[tid] = 0;
  __syncthreads();
  const int* tb = tmp + (size_t)b*cap;
  for (int i = tid; i < cnt; i += 256) atomicAdd(&h[tb[i] >> 17], 1);
  __syncthreads();
  if (tid < 128) sc[tid] = h[tid];
  __syncthreads();
  for (int off = 1; off < 128; off <<= 1){
    int x = (tid < 128 && tid >= off) ? sc[tid-off] : 0;
    __syncthreads();
    if (tid < 128) sc[tid] += x;
    __syncthreads();
  }
  if (tid < 128){
    int excl = sc[tid] - h[tid];
    int node = b*128 + tid;
    if (node < N) rowstart[node] = base + excl;
    cur[tid] = base + excl;
  }
  __syncthreads();
  for (int i = tid; i < cnt; i += 256){
    int v = tb[i];
    int p = atomicAdd(&cur[v >> 17], 1);
    csr[p] = v & 0x1FFFF;
  }
}

// ---------------- weight prep: f16 weights + att-folded tiles + bias consts ----------------
__global__ void k_prep(const float* __restrict__ W1, const float* __restrict__ b1,
                       const float* __restrict__ att1,
                       const float* __restrict__ W2, const float* __restrict__ b2,
                       const float* __restrict__ att2,
                       _Float16* __restrict__ W1h, _Float16* __restrict__ W2h,
                       _Float16* __restrict__ attB1, _Float16* __restrict__ attB2,
                       float* __restrict__ consts){
  int i = blockIdx.x*blockDim.x + threadIdx.x;
  if (i < 16384){ W1h[i] = (_Float16)W1[i]; return; }
  i -= 16384;
  if (i < 6144){ int r = i >> 7; W2h[i] = (r < 40)? (_Float16)W2[i] : (_Float16)0.f; return; }
  i -= 6144;
  if (i < 2048){
    int j = i >> 7, k = i & 127;
    int h = j & 7, half = (j >> 3)*16;
    float s = 0.f;
    for (int c = 0; c < 16; ++c) s += att1[h*32 + half + c]*W1[(h*16+c)*128 + k];
    attB1[i] = (_Float16)s; return;
  }
  i -= 2048;
  if (i < 2048){
    int j = i >> 7, k = i & 127;
    float s = 0.f;
    if (j < 2){ const float* av = att2 + j*40; for (int c = 0; c < 40; ++c) s += av[c]*W2[c*128 + k]; }
    attB2[i] = (_Float16)s; return;
  }
  i -= 2048;
  if (i < 18){
    float s = 0.f;
    if (i < 8){ for (int c = 0; c < 16; ++c) s += b1[i*16+c]*att1[i*32+c]; }
    else if (i < 16){ int h = i-8; for (int c = 0; c < 16; ++c) s += b1[h*16+c]*att1[h*32+16+c]; }
    else if (i == 16){ for (int c = 0; c < 40; ++c) s += b2[c]*att2[c]; }
    else { for (int c = 0; c < 40; ++c) s += b2[c]*att2[40+c]; }
    consts[i] = s;
  }
}

// ---------------- GEMM1 (MFMA f16): h1 (fp8, row-major) + a1i/a1j (fp32) ----------------
__global__ __launch_bounds__(256) void k_gemm1(const float* __restrict__ x,
    const _Float16* __restrict__ Wh, const _Float16* __restrict__ attB,
    const float* __restrict__ b1, const float* __restrict__ consts,
    unsigned char* __restrict__ h1f8, float* __restrict__ a1i, float* __restrict__ a1j, int N){
  int wid  = (blockIdx.x*256 + threadIdx.x) >> 6;
  int lane = threadIdx.x & 63;
  int m0 = wid*16;
  if (m0 >= N) return;
  int col = lane & 15, quad = lane >> 4;
  const float* xr = x + (size_t)(m0+col)*128 + quad*8;
  f32x4 acc[9];
  #pragma unroll
  for (int t=0;t<9;t++){ acc[t][0]=0.f; acc[t][1]=0.f; acc[t][2]=0.f; acc[t][3]=0.f; }
  #pragma unroll
  for (int q=0;q<4;q++){
    float4 f0 = ((const float4*)(xr + q*32))[0];
    float4 f1 = ((const float4*)(xr + q*32))[1];
    f16x8 a;
    a[0]=(_Float16)f0.x; a[1]=(_Float16)f0.y; a[2]=(_Float16)f0.z; a[3]=(_Float16)f0.w;
    a[4]=(_Float16)f1.x; a[5]=(_Float16)f1.y; a[6]=(_Float16)f1.z; a[7]=(_Float16)f1.w;
    #pragma unroll
    for (int t=0;t<8;t++){
      const f16x8* Bp = (const f16x8*)(Wh + (size_t)(t*16+col)*128 + q*32 + quad*8);
      acc[t] = __builtin_amdgcn_mfma_f32_16x16x32_f16(a, *Bp, acc[t], 0,0,0);
    }
    const f16x8* Ap = (const f16x8*)(attB + (size_t)col*128 + q*32 + quad*8);
    acc[8] = __builtin_amdgcn_mfma_f32_16x16x32_f16(a, *Ap, acc[8], 0,0,0);
  }
  #pragma unroll
  for (int t=0;t<8;t++){
    int c = t*16 + col;
    float bb = b1[c];
    #pragma unroll
    for (int r=0;r<4;r++){
      h1f8[(size_t)(m0 + quad*4 + r)*128 + c] = f2fp8(acc[t][r] + bb);
    }
  }
  float hb = consts[col];
  #pragma unroll
  for (int r=0;r<4;r++){
    int node = m0 + quad*4 + r;
    float v = acc[8][r] + hb;
    if (col < 8) a1i[node*8 + col] = v;
    else         a1j[node*8 + (col-8)] = v;
  }
}

// ---------------- layer-1 fused softmax+aggregate: 4-stage pipelined fp8 gather ----------------
__global__ __launch_bounds__(256) void k_agg1(const uint2* __restrict__ h1q,
    const float* __restrict__ a1i, const float* __restrict__ a1j,
    const int* __restrict__ rowstart, const int* __restrict__ csr,
    const float* __restrict__ bias, uint4* __restrict__ x2u4, int N){
  int lane = threadIdx.x & 63;
  int n = (blockIdx.x*blockDim.x + threadIdx.x) >> 6;
  if (n >= N) return;
  int ql = lane & 15, qt = lane >> 4;
  unsigned hd = (unsigned)ql >> 1;
  int rs = rowstart[n], re = rowstart[n+1];
  float ai2 = a1i[(unsigned)n*8u + hd];
  float a0=0.f,a1=0.f,a2=0.f,a3=0.f,a4=0.f,a5=0.f,a6=0.f,a7=0.f,den=0.f;
  {
    float w = (qt==0)? __expf(lrelu02(ai2 + a1j[(unsigned)n*8u + hd])) : 0.f;
    uint2 u = h1q[(unsigned)n*16u + (unsigned)ql];
    f32x2 f0 = __builtin_amdgcn_cvt_pk_f32_fp8((int)u.x, false);
    f32x2 f1 = __builtin_amdgcn_cvt_pk_f32_fp8((int)u.x, true);
    f32x2 f2 = __builtin_amdgcn_cvt_pk_f32_fp8((int)u.y, false);
    f32x2 f3 = __builtin_amdgcn_cvt_pk_f32_fp8((int)u.y, true);
    a0=w*f0[0]; a1=w*f0[1]; a2=w*f1[0]; a3=w*f1[1];
    a4=w*f2[0]; a5=w*f2[1]; a6=w*f3[0]; a7=w*f3[1];
    den = w;
  }
  int last = re - 1;
  if (rs < re){
    unsigned cs0 = (unsigned)csr[min(rs+0+qt,last)];
    unsigned cs1 = (unsigned)csr[min(rs+4+qt,last)];
    unsigned cs2 = (unsigned)csr[min(rs+8+qt,last)];
    unsigned cs3 = (unsigned)csr[min(rs+12+qt,last)];
    float aj0 = a1j[cs0*8u+hd], aj1 = a1j[cs1*8u+hd];
    float aj2 = a1j[cs2*8u+hd], aj3 = a1j[cs3*8u+hd];
    uint2 ua = h1q[(size_t)cs0*16u + (unsigned)ql];
    uint2 ub = h1q[(size_t)cs1*16u + (unsigned)ql];
    int e0 = rs;

#define AGG1_STAGE(AJ, CSPRE, CSSLOT, OFF)                                   \
    {                                                                        \
      uint2 uc = h1q[(size_t)CSPRE*16u + (unsigned)ql];                      \
      unsigned nc = (unsigned)csr[min(e0+OFF+16+qt, last)];                  \
      float w = (e0+OFF+qt < re)? __expf(lrelu02(ai2 + AJ)) : 0.f;           \
      den += w;                                                              \
      f32x2 g0 = __builtin_amdgcn_cvt_pk_f32_fp8((int)ua.x, false);          \
      f32x2 g1 = __builtin_amdgcn_cvt_pk_f32_fp8((int)ua.x, true);           \
      f32x2 g2 = __builtin_amdgcn_cvt_pk_f32_fp8((int)ua.y, false);          \
      f32x2 g3 = __builtin_amdgcn_cvt_pk_f32_fp8((int)ua.y, true);           \
      a0 += w*g0[0]; a1 += w*g0[1]; a2 += w*g1[0]; a3 += w*g1[1];            \
      a4 += w*g2[0]; a5 += w*g2[1]; a6 += w*g3[0]; a7 += w*g3[1];            \
      CSSLOT = nc; AJ = a1j[nc*8u + hd];                                     \
      ua = ub; ub = uc;                                                      \
    }

    while (e0 < re){
      AGG1_STAGE(aj0, cs2, cs0, 0)
      if (e0+4 >= re) break;
      AGG1_STAGE(aj1, cs3, cs1, 4)
      if (e0+8 >= re) break;
      AGG1_STAGE(aj2, cs0, cs2, 8)
      if (e0+12 >= re) break;
      AGG1_STAGE(aj3, cs1, cs3, 12)
      e0 += 16;
    }
#undef AGG1_STAGE
  }
  #pragma unroll
  for (int off = 16; off < 64; off <<= 1){
    den += __shfl_xor(den, off);
    a0 += __shfl_xor(a0, off); a1 += __shfl_xor(a1, off);
    a2 += __shfl_xor(a2, off); a3 += __shfl_xor(a3, off);
    a4 += __shfl_xor(a4, off); a5 += __shfl_xor(a5, off);
    a6 += __shfl_xor(a6, off); a7 += __shfl_xor(a7, off);
  }
  if (qt == 0){
    float invd = 1.f/(den + 1e-16f);
    const float4* b4 = (const float4*)(bias + 8*ql);
    float4 bl = b4[0], bh = b4[1];
    float o0=a0*invd+bl.x, o1=a1*invd+bl.y, o2=a2*invd+bl.z, o3=a3*invd+bl.w;
    float o4=a4*invd+bh.x, o5=a5*invd+bh.y, o6=a6*invd+bh.z, o7=a7*invd+bh.w;
    o0=(o0>0.f)?o0:(__expf(o0)-1.f); o1=(o1>0.f)?o1:(__expf(o1)-1.f);
    o2=(o2>0.f)?o2:(__expf(o2)-1.f); o3=(o3>0.f)?o3:(__expf(o3)-1.f);
    o4=(o4>0.f)?o4:(__expf(o4)-1.f); o5=(o5>0.f)?o5:(__expf(o5)-1.f);
    o6=(o6>0.f)?o6:(__expf(o6)-1.f); o7=(o7>0.f)?o7:(__expf(o7)-1.f);
    __half2 p0 = __floats2half2_rn(o0,o1), p1 = __floats2half2_rn(o2,o3);
    __half2 p2 = __floats2half2_rn(o4,o5), p3 = __floats2half2_rn(o6,o7);
    uint4 o;
    o.x = *(unsigned*)&p0; o.y = *(unsigned*)&p1; o.z = *(unsigned*)&p2; o.w = *(unsigned*)&p3;
    x2u4[(unsigned)n*16u + (unsigned)ql] = o;   // x2 stays f16 (MFMA A operand)
  }
}

// ---------------- GEMM2 (MFMA f16): h2 (fp8) + a2i/a2j ----------------
__global__ __launch_bounds__(256) void k_gemm2(const _Float16* __restrict__ xh,
    const _Float16* __restrict__ Wh, const _Float16* __restrict__ attB,
    const float* __restrict__ b2, const float* __restrict__ consts,
    unsigned char* __restrict__ h2f8, float* __restrict__ a2i, float* __restrict__ a2j, int N){
  int wid  = (blockIdx.x*256 + threadIdx.x) >> 6;
  int lane = threadIdx.x & 63;
  int m0 = wid*16;
  if (m0 >= N) return;
  int col = lane & 15, quad = lane >> 4;
  const f16x8* A8 = (const f16x8*)(xh + (size_t)(m0+col)*128 + quad*8);
  f32x4 acc[4];
  #pragma unroll
  for (int t=0;t<4;t++){ acc[t][0]=0.f; acc[t][1]=0.f; acc[t][2]=0.f; acc[t][3]=0.f; }
  #pragma unroll
  for (int q=0;q<4;q++){
    f16x8 a = A8[q*4];
    #pragma unroll
    for (int t=0;t<3;t++){
      const f16x8* Bp = (const f16x8*)(Wh + (size_t)(t*16+col)*128 + q*32 + quad*8);
      acc[t] = __builtin_amdgcn_mfma_f32_16x16x32_f16(a, *Bp, acc[t], 0,0,0);
    }
    const f16x8* Bp2 = (const f16x8*)(attB + (size_t)col*128 + q*32 + quad*8);
    acc[3] = __builtin_amdgcn_mfma_f32_16x16x32_f16(a, *Bp2, acc[3], 0,0,0);
  }
  #pragma unroll
  for (int t=0;t<3;t++){
    int c = t*16 + col;
    if (c < 40){
      float bb = b2[c];
      #pragma unroll
      for (int r=0;r<4;r++){
        h2f8[(size_t)(m0 + quad*4 + r)*40 + c] = f2fp8(acc[t][r] + bb);
      }
    }
  }
  if (col < 2){
    float cc = consts[16 + col];
    #pragma unroll
    for (int r=0;r<4;r++){
      int node = m0 + quad*4 + r;
      if (col == 0) a2i[node] = acc[3][r] + cc;
      else          a2j[node] = acc[3][r] + cc;
    }
  }
}

// ---------------- layer-2 fused softmax+aggregate + log_softmax ----------------
__global__ __launch_bounds__(256) void k_agg2(const unsigned* __restrict__ h2u,
    const float* __restrict__ a2i, const float* __restrict__ a2j,
    const int* __restrict__ rowstart, const int* __restrict__ csr,
    const float* __restrict__ bias, float* __restrict__ out, int N){
  int lane = threadIdx.x & 63;
  int wid = (blockIdx.x*blockDim.x + threadIdx.x) >> 6;
  int qt = lane >> 4, ql = lane & 15;
  int n = wid*4 + qt;
  if (n >= N) return;
  bool act = ql < 10;
  unsigned cl = act ? (unsigned)ql : 0u;
  int rs = rowstart[n], re = rowstart[n+1];
  float ai = a2i[n];
  float wself = __expf(lrelu02(ai + a2j[n]));
  float a0,a1,a2,a3,den;
  {
    unsigned u = h2u[(unsigned)n*10u + cl];
    f32x2 f0 = __builtin_amdgcn_cvt_pk_f32_fp8((int)u, false);
    f32x2 f1 = __builtin_amdgcn_cvt_pk_f32_fp8((int)u, true);
    a0 = wself*f0[0]; a1 = wself*f0[1]; a2 = wself*f1[0]; a3 = wself*f1[1];
    den = wself;
  }
  if (rs < re){
    int last = re - 1;
    unsigned cs0 = (unsigned)csr[min(rs+0,last)];
    unsigned cs1 = (unsigned)csr[min(rs+1,last)];
    unsigned cs2 = (unsigned)csr[min(rs+2,last)];
    unsigned cs3 = (unsigned)csr[min(rs+3,last)];
    float aj0 = a2j[cs0], aj1 = a2j[cs1], aj2 = a2j[cs2], aj3 = a2j[cs3];
    unsigned ua = h2u[cs0*10u + cl];
    unsigned ub = h2u[cs1*10u + cl];
    int e0 = rs;

#define AGG2_STAGE(AJ, CSPRE, CSSLOT, OFF)                                   \
    {                                                                        \
      unsigned uc = h2u[CSPRE*10u + cl];                                     \
      unsigned nc = (unsigned)csr[min(e0+OFF+4, last)];                      \
      float w = (e0+OFF < re)? __expf(lrelu02(ai + AJ)) : 0.f;               \
      den += w;                                                              \
      f32x2 g0 = __builtin_amdgcn_cvt_pk_f32_fp8((int)ua, false);            \
      f32x2 g1 = __builtin_amdgcn_cvt_pk_f32_fp8((int)ua, true);             \
      a0 += w*g0[0]; a1 += w*g0[1]; a2 += w*g1[0]; a3 += w*g1[1];            \
      CSSLOT = nc; AJ = a2j[nc];                                             \
      ua = ub; ub = uc;                                                      \
    }

    while (e0 < re){
      AGG2_STAGE(aj0, cs2, cs0, 0)
      AGG2_STAGE(aj1, cs3, cs1, 1)
      AGG2_STAGE(aj2, cs0, cs2, 2)
      AGG2_STAGE(aj3, cs1, cs3, 3)
      e0 += 4;
    }
#undef AGG2_STAGE
  }
  float invd = 1.f/(den + 1e-16f);
  const float4* b4 = (const float4*)(bias + 4*cl);
  float4 bb = b4[0];
  float v0 = a0*invd + bb.x, v1 = a1*invd + bb.y;
  float v2 = a2*invd + bb.z, v3 = a3*invd + bb.w;
  float mv = act ? fmaxf(fmaxf(v0,v1), fmaxf(v2,v3)) : -INFINITY;
  #pragma unroll
  for (int off = 1; off < 16; off <<= 1) mv = fmaxf(mv, __shfl_xor(mv, off));
  float se = act ? (__expf(v0-mv)+__expf(v1-mv)+__expf(v2-mv)+__expf(v3-mv)) : 0.f;
  #pragma unroll
  for (int off = 1; off < 16; off <<= 1) se += __shfl_xor(se, off);
  float ls = __logf(se);
  if (act){
    float4 o = make_float4(v0-mv-ls, v1-mv-ls, v2-mv-ls, v3-mv-ls);
    ((float4*)out)[(unsigned)n*10u + cl] = o;
  }
}

extern "C" void kernel_launch(void* const* d_in, const int* in_sizes, int n_in,
                              void* d_out, int out_size, void* d_ws, size_t ws_size,
                              hipStream_t stream){
  const float* x     = (const float*)d_in[0];
  const int*   ei    = (const int*)  d_in[1];
  const float* W1    = (const float*)d_in[2];
  const float* b1    = (const float*)d_in[3];
  const float* att1  = (const float*)d_in[4];
  const float* bias1 = (const float*)d_in[5];
  const float* W2    = (const float*)d_in[6];
  const float* b2    = (const float*)d_in[7];
  const float* att2  = (const float*)d_in[8];
  const float* bias2 = (const float*)d_in[9];
  int N = in_sizes[0] / 128;
  int E = in_sizes[1] / 2;
  const int* src = ei;
  const int* dst = ei + E;

  char* ws = (char*)d_ws;
  size_t off = 0;
  auto alloc = [&](size_t bytes)->char*{
    char* p = ws + off; off += (bytes + 255) & ~(size_t)255; return p;
  };
  unsigned char* h1f8 = (unsigned char*)alloc((size_t)N*128);   // fp8 row-major
  _Float16*      x2h  = (_Float16*)alloc((size_t)N*128*2);      // f16 (MFMA A)
  unsigned char* h2f8 = (unsigned char*)alloc((size_t)N*40);    // fp8 row-major
  float* a1i  = (float*)alloc((size_t)N*8*4);
  float* a1j  = (float*)alloc((size_t)N*8*4);
  float* a2i  = (float*)alloc((size_t)N*4);
  float* a2j  = (float*)alloc((size_t)N*4);
  _Float16* W1h   = (_Float16*)alloc(16384*2);
  _Float16* W2h   = (_Float16*)alloc(6144*2);
  _Float16* attB1 = (_Float16*)alloc(2048*2);
  _Float16* attB2 = (_Float16*)alloc(2048*2);
  float* consts = (float*)alloc(18*4);
  int*   rowst = (int*)  alloc((size_t)(N+1)*4);
  int*   csr   = (int*)  alloc((size_t)E*4);

  int nbucket = (N + BMASK) >> BSHIFT;           // <= 1024 for N <= 131072
  int meanb = (E + nbucket - 1)/nbucket;
  int cap = ((2*meanb + 1023)/1024)*1024;        // ~2x mean: +dozens of sigma
  if (cap < 2048) cap = 2048;

  int*   gcur   = (int*)alloc((size_t)nbucket*64);   // 1 counter per 64B line
  int*   bstart = (int*)alloc((size_t)(nbucket+1)*4);
  int*   tmp    = (int*)x2h;                         // alias: dead until k_agg1

  int nchunk = (E + SPLIT_CHUNK - 1)/SPLIT_CHUNK;
  k_initcur<<<(nbucket+255)/256, 256, 0, stream>>>(gcur, nbucket, cap);
  k_split<<<nchunk, 256, 0, stream>>>(src, dst, gcur, tmp, E, nbucket);
  k_bscan<<<1, 256, 0, stream>>>(gcur, bstart, rowst, nbucket, cap, E, N);
  k_final<<<nbucket, 256, 0, stream>>>(tmp, gcur, bstart, rowst, csr, cap, N);
  k_prep<<<105, 256, 0, stream>>>(W1, b1, att1, W2, b2, att2, W1h, W2h, attB1, attB2, consts);

  int gblk = ((N+15)/16 + 3)/4;  // 4 waves/block, 16 nodes/wave
  k_gemm1<<<gblk, 256, 0, stream>>>(x, W1h, attB1, b1, consts, h1f8, a1i, a1j, N);
  k_agg1<<<(N*64+255)/256, 256, 0, stream>>>((const uint2*)h1f8, a1i, a1j, rowst, csr, bias1, (uint4*)x2h, N);

  k_gemm2<<<gblk, 256, 0, stream>>>(x2h, W2h, attB2, b2, consts, h2f8, a2i, a2j, N);
  k_agg2<<<(N+15)/16, 256, 0, stream>>>((const unsigned*)h2f8, a2i, a2j, rowst, csr, bias2, (float*)d_out, N);
}

// Round 3
// 315.464 us; speedup vs baseline: 1.5321x; 1.0222x over previous
//
#include <hip/hip_runtime.h>
#include <hip/hip_fp16.h>
#include <math.h>

// 2-layer GAT. f16 MFMA GEMMs (fused attention-scalar B-tiles, fused fp32->f16
// A-convert), fp8-e4m3 feature storage for the edge gathers, single-pass
// segment softmax, fp32 accumulation.
//
// CSR build (R13): two-level multi-split dodges the ~22G/s global-atomic wall
// (one device atomic per (block,bucket) ~300K instead of per-edge 1.6M).
//
// Aggregation (R14): k_agg1 measured 2.55 TB/s at the L2-miss boundary =
// 1 line per ~15 cy per CU = exactly 23 waves/CU x 2 outstanding / 600 cy
// latency -> latency*MLP-bound, NOT bandwidth-bound. Fix: 8-stage statically-
// unrolled pipeline; cs/aj rings 8 deep (csr prefetched 32 edges ahead),
// feature ring 4 live loads (issued 16 edges ahead), consume-then-reissue
// same named register slot (ring 4 divides 8 stages -> all slot names static,
// no runtime-indexed register arrays - R11 lesson). Same for k_agg2.

typedef _Float16 f16x8 __attribute__((ext_vector_type(8)));   // 8 f16 (4 VGPRs)
typedef float f32x4 __attribute__((ext_vector_type(4)));
typedef float f32x2 __attribute__((ext_vector_type(2)));

__device__ __forceinline__ float lrelu02(float x){ return x > 0.f ? x : 0.2f*x; }
__device__ __forceinline__ unsigned char f2fp8(float v){
  return (unsigned char)(__builtin_amdgcn_cvt_pk_fp8_f32(v, v, 0, false) & 0xff);
}

#define BSHIFT 7                 // 128 nodes per bucket (N <= 131072)
#define BMASK  127
#define SPLIT_CHUNK 4096         // edges per split block

__global__ void k_initcur(int* __restrict__ gcur, int nbucket, int cap){
  int b = blockIdx.x*blockDim.x + threadIdx.x;
  if (b < nbucket) gcur[b*16] = b*cap;
}

// ---------------- multi-split: bucket-group edges into tmp ----------------
__global__ __launch_bounds__(256) void k_split(const int* __restrict__ src,
    const int* __restrict__ dst, int* __restrict__ gcur, int* __restrict__ tmp,
    int E, int nbucket){
  __shared__ int hist[1024];
  int tid = threadIdx.x;
  for (int t = tid; t < 1024; t += 256) hist[t] = 0;
  __syncthreads();
  int lo = blockIdx.x*SPLIT_CHUNK;
  int ds[16], ss[16];
  #pragma unroll
  for (int k = 0; k < 16; ++k){
    int i = lo + tid + k*256;
    bool p = i < E;
    ds[k] = p ? dst[i] : 0;
    ss[k] = p ? src[i] : 0;
    if (p) atomicAdd(&hist[ds[k] >> BSHIFT], 1);     // LDS atomic
  }
  __syncthreads();
  // one device atomic per nonzero bucket; reuse hist[] to hold absolute base
  for (int b = tid; b < nbucket; b += 256){
    int c = hist[b];
    if (c) hist[b] = atomicAdd(&gcur[b*16], c);
  }
  __syncthreads();
  #pragma unroll
  for (int k = 0; k < 16; ++k){
    int i = lo + tid + k*256;
    if (i < E){
      int r = atomicAdd(&hist[ds[k] >> BSHIFT], 1);  // LDS atomic, abs position
      tmp[r] = ss[k] | ((ds[k] & BMASK) << 17);
    }
  }
}

// ---------------- bucket scan: counts -> bucketStart (exclusive) ----------------
__global__ void k_bscan(const int* __restrict__ gcur, int* __restrict__ bstart,
                        int* __restrict__ rowstart, int nbucket, int cap, int E, int N){
  __shared__ int lds[256];
  int t = threadIdx.x;
  int v[4]; int s = 0;
  #pragma unroll
  for (int k = 0; k < 4; ++k){
    int idx = t*4 + k;
    v[k] = (idx < nbucket) ? (gcur[idx*16] - idx*cap) : 0;
    s += v[k];
  }
  lds[t] = s;
  __syncthreads();
  for (int off = 1; off < 256; off <<= 1){
    int x = (t >= off) ? lds[t-off] : 0;
    __syncthreads();
    lds[t] += x;
    __syncthreads();
  }
  int run = (t == 0) ? 0 : lds[t-1];
  #pragma unroll
  for (int k = 0; k < 4; ++k){
    int idx = t*4 + k;
    if (idx < nbucket) bstart[idx] = run;
    run += v[k];
  }
  if (t == 0){ bstart[nbucket] = E; rowstart[N] = E; }
}

// ---------------- finalize: per-bucket node hist + scan -> rowstart + csr ----------------
__global__ __launch_bounds__(256) void k_final(const int* __restrict__ tmp,
    const int* __restrict__ gcur, const int* __restrict__ bstart,
    int* __restrict__ rowstart, int* __restrict__ csr, int cap, int N){
  __shared__ int h[128];
  __shared__ int sc[128];
  __shared__ int cur[128];
  int b = blockIdx.x;
  int tid = threadIdx.x;
  int cnt  = gcur[b*16] - b*cap;
  int base = bstart[b];
  if (tid < 128) h[tid] = 0;
  __syncthreads();
  const int* tb = tmp + (size_t)b*cap;
  for (int i = tid; i < cnt; i += 256) atomicAdd(&h[tb[i] >> 17], 1);
  __syncthreads();
  if (tid < 128) sc[tid] = h[tid];
  __syncthreads();
  for (int off = 1; off < 128; off <<= 1){
    int x = (tid < 128 && tid >= off) ? sc[tid-off] : 0;
    __syncthreads();
    if (tid < 128) sc[tid] += x;
    __syncthreads();
  }
  if (tid < 128){
    int excl = sc[tid] - h[tid];
    int node = b*128 + tid;
    if (node < N) rowstart[node] = base + excl;
    cur[tid] = base + excl;
  }
  __syncthreads();
  for (int i = tid; i < cnt; i += 256){
    int v = tb[i];
    int p = atomicAdd(&cur[v >> 17], 1);
    csr[p] = v & 0x1FFFF;
  }
}

// ---------------- weight prep: f16 weights + att-folded tiles + bias consts ----------------
__global__ void k_prep(const float* __restrict__ W1, const float* __restrict__ b1,
                       const float* __restrict__ att1,
                       const float* __restrict__ W2, const float* __restrict__ b2,
                       const float* __restrict__ att2,
                       _Float16* __restrict__ W1h, _Float16* __restrict__ W2h,
                       _Float16* __restrict__ attB1, _Float16* __restrict__ attB2,
                       float* __restrict__ consts){
  int i = blockIdx.x*blockDim.x + threadIdx.x;
  if (i < 16384){ W1h[i] = (_Float16)W1[i]; return; }
  i -= 16384;
  if (i < 6144){ int r = i >> 7; W2h[i] = (r < 40)? (_Float16)W2[i] : (_Float16)0.f; return; }
  i -= 6144;
  if (i < 2048){
    int j = i >> 7, k = i & 127;
    int h = j & 7, half = (j >> 3)*16;
    float s = 0.f;
    for (int c = 0; c < 16; ++c) s += att1[h*32 + half + c]*W1[(h*16+c)*128 + k];
    attB1[i] = (_Float16)s; return;
  }
  i -= 2048;
  if (i < 2048){
    int j = i >> 7, k = i & 127;
    float s = 0.f;
    if (j < 2){ const float* av = att2 + j*40; for (int c = 0; c < 40; ++c) s += av[c]*W2[c*128 + k]; }
    attB2[i] = (_Float16)s; return;
  }
  i -= 2048;
  if (i < 18){
    float s = 0.f;
    if (i < 8){ for (int c = 0; c < 16; ++c) s += b1[i*16+c]*att1[i*32+c]; }
    else if (i < 16){ int h = i-8; for (int c = 0; c < 16; ++c) s += b1[h*16+c]*att1[h*32+16+c]; }
    else if (i == 16){ for (int c = 0; c < 40; ++c) s += b2[c]*att2[c]; }
    else { for (int c = 0; c < 40; ++c) s += b2[c]*att2[40+c]; }
    consts[i] = s;
  }
}

// ---------------- GEMM1 (MFMA f16): h1 (fp8, row-major) + a1i/a1j (fp32) ----------------
__global__ __launch_bounds__(256) void k_gemm1(const float* __restrict__ x,
    const _Float16* __restrict__ Wh, const _Float16* __restrict__ attB,
    const float* __restrict__ b1, const float* __restrict__ consts,
    unsigned char* __restrict__ h1f8, float* __restrict__ a1i, float* __restrict__ a1j, int N){
  int wid  = (blockIdx.x*256 + threadIdx.x) >> 6;
  int lane = threadIdx.x & 63;
  int m0 = wid*16;
  if (m0 >= N) return;
  int col = lane & 15, quad = lane >> 4;
  const float* xr = x + (size_t)(m0+col)*128 + quad*8;
  f32x4 acc[9];
  #pragma unroll
  for (int t=0;t<9;t++){ acc[t][0]=0.f; acc[t][1]=0.f; acc[t][2]=0.f; acc[t][3]=0.f; }
  #pragma unroll
  for (int q=0;q<4;q++){
    float4 f0 = ((const float4*)(xr + q*32))[0];
    float4 f1 = ((const float4*)(xr + q*32))[1];
    f16x8 a;
    a[0]=(_Float16)f0.x; a[1]=(_Float16)f0.y; a[2]=(_Float16)f0.z; a[3]=(_Float16)f0.w;
    a[4]=(_Float16)f1.x; a[5]=(_Float16)f1.y; a[6]=(_Float16)f1.z; a[7]=(_Float16)f1.w;
    #pragma unroll
    for (int t=0;t<8;t++){
      const f16x8* Bp = (const f16x8*)(Wh + (size_t)(t*16+col)*128 + q*32 + quad*8);
      acc[t] = __builtin_amdgcn_mfma_f32_16x16x32_f16(a, *Bp, acc[t], 0,0,0);
    }
    const f16x8* Ap = (const f16x8*)(attB + (size_t)col*128 + q*32 + quad*8);
    acc[8] = __builtin_amdgcn_mfma_f32_16x16x32_f16(a, *Ap, acc[8], 0,0,0);
  }
  #pragma unroll
  for (int t=0;t<8;t++){
    int c = t*16 + col;
    float bb = b1[c];
    #pragma unroll
    for (int r=0;r<4;r++){
      h1f8[(size_t)(m0 + quad*4 + r)*128 + c] = f2fp8(acc[t][r] + bb);
    }
  }
  float hb = consts[col];
  #pragma unroll
  for (int r=0;r<4;r++){
    int node = m0 + quad*4 + r;
    float v = acc[8][r] + hb;
    if (col < 8) a1i[node*8 + col] = v;
    else         a1j[node*8 + (col-8)] = v;
  }
}

// ---------------- layer-1 fused softmax+aggregate: 8-stage pipelined fp8 gather ----------------
// one wave per node; quarter qt owns edge e+qt of each group of 4; lane ql owns
// channels 8*ql..8*ql+7 (uint2 of fp8), head = ql>>1. cs/aj rings 8 deep
// (csr 32 edges ahead); feature ring u0..u3 (issued 16 edges ahead). fp32 accum.
__global__ __launch_bounds__(256) void k_agg1(const uint2* __restrict__ h1q,
    const float* __restrict__ a1i, const float* __restrict__ a1j,
    const int* __restrict__ rowstart, const int* __restrict__ csr,
    const float* __restrict__ bias, uint4* __restrict__ x2u4, int N){
  int lane = threadIdx.x & 63;
  int n = (blockIdx.x*blockDim.x + threadIdx.x) >> 6;
  if (n >= N) return;
  int ql = lane & 15, qt = lane >> 4;
  unsigned hd = (unsigned)ql >> 1;
  int rs = rowstart[n], re = rowstart[n+1];
  float ai2 = a1i[(unsigned)n*8u + hd];
  float a0=0.f,a1=0.f,a2=0.f,a3=0.f,a4=0.f,a5=0.f,a6=0.f,a7=0.f,den=0.f;
  {
    float w = (qt==0)? __expf(lrelu02(ai2 + a1j[(unsigned)n*8u + hd])) : 0.f;
    uint2 u = h1q[(unsigned)n*16u + (unsigned)ql];
    f32x2 f0 = __builtin_amdgcn_cvt_pk_f32_fp8((int)u.x, false);
    f32x2 f1 = __builtin_amdgcn_cvt_pk_f32_fp8((int)u.x, true);
    f32x2 f2 = __builtin_amdgcn_cvt_pk_f32_fp8((int)u.y, false);
    f32x2 f3 = __builtin_amdgcn_cvt_pk_f32_fp8((int)u.y, true);
    a0=w*f0[0]; a1=w*f0[1]; a2=w*f1[0]; a3=w*f1[1];
    a4=w*f2[0]; a5=w*f2[1]; a6=w*f3[0]; a7=w*f3[1];
    den = w;
  }
  int last = re - 1;
  if (rs < re){
    unsigned cs0 = (unsigned)csr[min(rs+ 0+qt,last)];
    unsigned cs1 = (unsigned)csr[min(rs+ 4+qt,last)];
    unsigned cs2 = (unsigned)csr[min(rs+ 8+qt,last)];
    unsigned cs3 = (unsigned)csr[min(rs+12+qt,last)];
    unsigned cs4 = (unsigned)csr[min(rs+16+qt,last)];
    unsigned cs5 = (unsigned)csr[min(rs+20+qt,last)];
    unsigned cs6 = (unsigned)csr[min(rs+24+qt,last)];
    unsigned cs7 = (unsigned)csr[min(rs+28+qt,last)];
    float aj0 = a1j[cs0*8u+hd], aj1 = a1j[cs1*8u+hd];
    float aj2 = a1j[cs2*8u+hd], aj3 = a1j[cs3*8u+hd];
    float aj4 = a1j[cs4*8u+hd], aj5 = a1j[cs5*8u+hd];
    float aj6 = a1j[cs6*8u+hd], aj7 = a1j[cs7*8u+hd];
    uint2 u0 = h1q[(size_t)cs0*16u + (unsigned)ql];
    uint2 u1 = h1q[(size_t)cs1*16u + (unsigned)ql];
    uint2 u2 = h1q[(size_t)cs2*16u + (unsigned)ql];
    uint2 u3 = h1q[(size_t)cs3*16u + (unsigned)ql];
    int e0 = rs;

// stage: consume US (edge e0+OFF+qt), reissue US with feature of edge +16
// (via CF = cs slot holding edge OFF+16), refresh CS/AJ with edge OFF+32.
#define AGG1_ST(US, CF, CS, AJ, OFF)                                         \
    {                                                                        \
      uint2 cur = US;                                                        \
      US = h1q[(size_t)CF*16u + (unsigned)ql];                               \
      unsigned nc = (unsigned)csr[min(e0+OFF+32+qt, last)];                  \
      float w = (e0+OFF+qt < re)? __expf(lrelu02(ai2 + AJ)) : 0.f;           \
      den += w;                                                              \
      f32x2 g0 = __builtin_amdgcn_cvt_pk_f32_fp8((int)cur.x, false);         \
      f32x2 g1 = __builtin_amdgcn_cvt_pk_f32_fp8((int)cur.x, true);          \
      f32x2 g2 = __builtin_amdgcn_cvt_pk_f32_fp8((int)cur.y, false);         \
      f32x2 g3 = __builtin_amdgcn_cvt_pk_f32_fp8((int)cur.y, true);          \
      a0 += w*g0[0]; a1 += w*g0[1]; a2 += w*g1[0]; a3 += w*g1[1];            \
      a4 += w*g2[0]; a5 += w*g2[1]; a6 += w*g3[0]; a7 += w*g3[1];            \
      CS = nc; AJ = a1j[nc*8u + hd];                                         \
    }

    while (e0 < re){
      AGG1_ST(u0, cs4, cs0, aj0, 0)
      if (e0+4 >= re) break;
      AGG1_ST(u1, cs5, cs1, aj1, 4)
      if (e0+8 >= re) break;
      AGG1_ST(u2, cs6, cs2, aj2, 8)
      if (e0+12 >= re) break;
      AGG1_ST(u3, cs7, cs3, aj3, 12)
      if (e0+16 >= re) break;
      AGG1_ST(u0, cs0, cs4, aj4, 16)
      if (e0+20 >= re) break;
      AGG1_ST(u1, cs1, cs5, aj5, 20)
      if (e0+24 >= re) break;
      AGG1_ST(u2, cs2, cs6, aj6, 24)
      if (e0+28 >= re) break;
      AGG1_ST(u3, cs3, cs7, aj7, 28)
      e0 += 32;
    }
#undef AGG1_ST
  }
  #pragma unroll
  for (int off = 16; off < 64; off <<= 1){
    den += __shfl_xor(den, off);
    a0 += __shfl_xor(a0, off); a1 += __shfl_xor(a1, off);
    a2 += __shfl_xor(a2, off); a3 += __shfl_xor(a3, off);
    a4 += __shfl_xor(a4, off); a5 += __shfl_xor(a5, off);
    a6 += __shfl_xor(a6, off); a7 += __shfl_xor(a7, off);
  }
  if (qt == 0){
    float invd = 1.f/(den + 1e-16f);
    const float4* b4 = (const float4*)(bias + 8*ql);
    float4 bl = b4[0], bh = b4[1];
    float o0=a0*invd+bl.x, o1=a1*invd+bl.y, o2=a2*invd+bl.z, o3=a3*invd+bl.w;
    float o4=a4*invd+bh.x, o5=a5*invd+bh.y, o6=a6*invd+bh.z, o7=a7*invd+bh.w;
    o0=(o0>0.f)?o0:(__expf(o0)-1.f); o1=(o1>0.f)?o1:(__expf(o1)-1.f);
    o2=(o2>0.f)?o2:(__expf(o2)-1.f); o3=(o3>0.f)?o3:(__expf(o3)-1.f);
    o4=(o4>0.f)?o4:(__expf(o4)-1.f); o5=(o5>0.f)?o5:(__expf(o5)-1.f);
    o6=(o6>0.f)?o6:(__expf(o6)-1.f); o7=(o7>0.f)?o7:(__expf(o7)-1.f);
    __half2 p0 = __floats2half2_rn(o0,o1), p1 = __floats2half2_rn(o2,o3);
    __half2 p2 = __floats2half2_rn(o4,o5), p3 = __floats2half2_rn(o6,o7);
    uint4 o;
    o.x = *(unsigned*)&p0; o.y = *(unsigned*)&p1; o.z = *(unsigned*)&p2; o.w = *(unsigned*)&p3;
    x2u4[(unsigned)n*16u + (unsigned)ql] = o;   // x2 stays f16 (MFMA A operand)
  }
}

// ---------------- GEMM2 (MFMA f16): h2 (fp8) + a2i/a2j ----------------
__global__ __launch_bounds__(256) void k_gemm2(const _Float16* __restrict__ xh,
    const _Float16* __restrict__ Wh, const _Float16* __restrict__ attB,
    const float* __restrict__ b2, const float* __restrict__ consts,
    unsigned char* __restrict__ h2f8, float* __restrict__ a2i, float* __restrict__ a2j, int N){
  int wid  = (blockIdx.x*256 + threadIdx.x) >> 6;
  int lane = threadIdx.x & 63;
  int m0 = wid*16;
  if (m0 >= N) return;
  int col = lane & 15, quad = lane >> 4;
  const f16x8* A8 = (const f16x8*)(xh + (size_t)(m0+col)*128 + quad*8);
  f32x4 acc[4];
  #pragma unroll
  for (int t=0;t<4;t++){ acc[t][0]=0.f; acc[t][1]=0.f; acc[t][2]=0.f; acc[t][3]=0.f; }
  #pragma unroll
  for (int q=0;q<4;q++){
    f16x8 a = A8[q*4];
    #pragma unroll
    for (int t=0;t<3;t++){
      const f16x8* Bp = (const f16x8*)(Wh + (size_t)(t*16+col)*128 + q*32 + quad*8);
      acc[t] = __builtin_amdgcn_mfma_f32_16x16x32_f16(a, *Bp, acc[t], 0,0,0);
    }
    const f16x8* Bp2 = (const f16x8*)(attB + (size_t)col*128 + q*32 + quad*8);
    acc[3] = __builtin_amdgcn_mfma_f32_16x16x32_f16(a, *Bp2, acc[3], 0,0,0);
  }
  #pragma unroll
  for (int t=0;t<3;t++){
    int c = t*16 + col;
    if (c < 40){
      float bb = b2[c];
      #pragma unroll
      for (int r=0;r<4;r++){
        h2f8[(size_t)(m0 + quad*4 + r)*40 + c] = f2fp8(acc[t][r] + bb);
      }
    }
  }
  if (col < 2){
    float cc = consts[16 + col];
    #pragma unroll
    for (int r=0;r<4;r++){
      int node = m0 + quad*4 + r;
      if (col == 0) a2i[node] = acc[3][r] + cc;
      else          a2j[node] = acc[3][r] + cc;
    }
  }
}

// ---------------- layer-2 fused softmax+aggregate + log_softmax ----------------
// FOUR nodes per wave (quarters); lanes ql<10 own 4 channels (uint of fp8).
// Per-quarter divergent edge loop, 8-stage pipeline: cs/aj rings 8 deep,
// feature ring 4 (issued 4 edges ahead). fp32 accumulation.
__global__ __launch_bounds__(256) void k_agg2(const unsigned* __restrict__ h2u,
    const float* __restrict__ a2i, const float* __restrict__ a2j,
    const int* __restrict__ rowstart, const int* __restrict__ csr,
    const float* __restrict__ bias, float* __restrict__ out, int N){
  int lane = threadIdx.x & 63;
  int wid = (blockIdx.x*blockDim.x + threadIdx.x) >> 6;
  int qt = lane >> 4, ql = lane & 15;
  int n = wid*4 + qt;
  if (n >= N) return;
  bool act = ql < 10;
  unsigned cl = act ? (unsigned)ql : 0u;
  int rs = rowstart[n], re = rowstart[n+1];
  float ai = a2i[n];
  float wself = __expf(lrelu02(ai + a2j[n]));
  float a0,a1,a2,a3,den;
  {
    unsigned u = h2u[(unsigned)n*10u + cl];
    f32x2 f0 = __builtin_amdgcn_cvt_pk_f32_fp8((int)u, false);
    f32x2 f1 = __builtin_amdgcn_cvt_pk_f32_fp8((int)u, true);
    a0 = wself*f0[0]; a1 = wself*f0[1]; a2 = wself*f1[0]; a3 = wself*f1[1];
    den = wself;
  }
  if (rs < re){
    int last = re - 1;
    unsigned cs0 = (unsigned)csr[min(rs+0,last)];
    unsigned cs1 = (unsigned)csr[min(rs+1,last)];
    unsigned cs2 = (unsigned)csr[min(rs+2,last)];
    unsigned cs3 = (unsigned)csr[min(rs+3,last)];
    unsigned cs4 = (unsigned)csr[min(rs+4,last)];
    unsigned cs5 = (unsigned)csr[min(rs+5,last)];
    unsigned cs6 = (unsigned)csr[min(rs+6,last)];
    unsigned cs7 = (unsigned)csr[min(rs+7,last)];
    float aj0 = a2j[cs0], aj1 = a2j[cs1], aj2 = a2j[cs2], aj3 = a2j[cs3];
    float aj4 = a2j[cs4], aj5 = a2j[cs5], aj6 = a2j[cs6], aj7 = a2j[cs7];
    unsigned u0 = h2u[cs0*10u + cl];
    unsigned u1 = h2u[cs1*10u + cl];
    unsigned u2 = h2u[cs2*10u + cl];
    unsigned u3 = h2u[cs3*10u + cl];
    int e0 = rs;

#define AGG2_ST(US, CF, CS, AJ, OFF)                                         \
    {                                                                        \
      unsigned cur = US;                                                     \
      US = h2u[CF*10u + cl];                                                 \
      unsigned nc = (unsigned)csr[min(e0+OFF+8, last)];                      \
      float w = (e0+OFF < re)? __expf(lrelu02(ai + AJ)) : 0.f;               \
      den += w;                                                              \
      f32x2 g0 = __builtin_amdgcn_cvt_pk_f32_fp8((int)cur, false);           \
      f32x2 g1 = __builtin_amdgcn_cvt_pk_f32_fp8((int)cur, true);            \
      a0 += w*g0[0]; a1 += w*g0[1]; a2 += w*g1[0]; a3 += w*g1[1];            \
      CS = nc; AJ = a2j[nc];                                                 \
    }

    while (e0 < re){
      AGG2_ST(u0, cs4, cs0, aj0, 0)
      AGG2_ST(u1, cs5, cs1, aj1, 1)
      AGG2_ST(u2, cs6, cs2, aj2, 2)
      AGG2_ST(u3, cs7, cs3, aj3, 3)
      AGG2_ST(u0, cs0, cs4, aj4, 4)
      AGG2_ST(u1, cs1, cs5, aj5, 5)
      AGG2_ST(u2, cs2, cs6, aj6, 6)
      AGG2_ST(u3, cs3, cs7, aj7, 7)
      e0 += 8;
    }
#undef AGG2_ST
  }
  float invd = 1.f/(den + 1e-16f);
  const float4* b4 = (const float4*)(bias + 4*cl);
  float4 bb = b4[0];
  float v0 = a0*invd + bb.x, v1 = a1*invd + bb.y;
  float v2 = a2*invd + bb.z, v3 = a3*invd + bb.w;
  float mv = act ? fmaxf(fmaxf(v0,v1), fmaxf(v2,v3)) : -INFINITY;
  #pragma unroll
  for (int off = 1; off < 16; off <<= 1) mv = fmaxf(mv, __shfl_xor(mv, off));
  float se = act ? (__expf(v0-mv)+__expf(v1-mv)+__expf(v2-mv)+__expf(v3-mv)) : 0.f;
  #pragma unroll
  for (int off = 1; off < 16; off <<= 1) se += __shfl_xor(se, off);
  float ls = __logf(se);
  if (act){
    float4 o = make_float4(v0-mv-ls, v1-mv-ls, v2-mv-ls, v3-mv-ls);
    ((float4*)out)[(unsigned)n*10u + cl] = o;
  }
}

extern "C" void kernel_launch(void* const* d_in, const int* in_sizes, int n_in,
                              void* d_out, int out_size, void* d_ws, size_t ws_size,
                              hipStream_t stream){
  const float* x     = (const float*)d_in[0];
  const int*   ei    = (const int*)  d_in[1];
  const float* W1    = (const float*)d_in[2];
  const float* b1    = (const float*)d_in[3];
  const float* att1  = (const float*)d_in[4];
  const float* bias1 = (const float*)d_in[5];
  const float* W2    = (const float*)d_in[6];
  const float* b2    = (const float*)d_in[7];
  const float* att2  = (const float*)d_in[8];
  const float* bias2 = (const float*)d_in[9];
  int N = in_sizes[0] / 128;
  int E = in_sizes[1] / 2;
  const int* src = ei;
  const int* dst = ei + E;

  char* ws = (char*)d_ws;
  size_t off = 0;
  auto alloc = [&](size_t bytes)->char*{
    char* p = ws + off; off += (bytes + 255) & ~(size_t)255; return p;
  };
  unsigned char* h1f8 = (unsigned char*)alloc((size_t)N*128);   // fp8 row-major
  _Float16*      x2h  = (_Float16*)alloc((size_t)N*128*2);      // f16 (MFMA A)
  unsigned char* h2f8 = (unsigned char*)alloc((size_t)N*40);    // fp8 row-major
  float* a1i  = (float*)alloc((size_t)N*8*4);
  float* a1j  = (float*)alloc((size_t)N*8*4);
  float* a2i  = (float*)alloc((size_t)N*4);
  float* a2j  = (float*)alloc((size_t)N*4);
  _Float16* W1h   = (_Float16*)alloc(16384*2);
  _Float16* W2h   = (_Float16*)alloc(6144*2);
  _Float16* attB1 = (_Float16*)alloc(2048*2);
  _Float16* attB2 = (_Float16*)alloc(2048*2);
  float* consts = (float*)alloc(18*4);
  int*   rowst = (int*)  alloc((size_t)(N+1)*4);
  int*   csr   = (int*)  alloc((size_t)E*4);

  int nbucket = (N + BMASK) >> BSHIFT;           // <= 1024 for N <= 131072
  int meanb = (E + nbucket - 1)/nbucket;
  int cap = ((2*meanb + 1023)/1024)*1024;        // ~2x mean: +dozens of sigma
  if (cap < 2048) cap = 2048;

  int*   gcur   = (int*)alloc((size_t)nbucket*64);   // 1 counter per 64B line
  int*   bstart = (int*)alloc((size_t)(nbucket+1)*4);
  int*   tmp    = (int*)x2h;                         // alias: dead until k_agg1

  int nchunk = (E + SPLIT_CHUNK - 1)/SPLIT_CHUNK;
  k_initcur<<<(nbucket+255)/256, 256, 0, stream>>>(gcur, nbucket, cap);
  k_split<<<nchunk, 256, 0, stream>>>(src, dst, gcur, tmp, E, nbucket);
  k_bscan<<<1, 256, 0, stream>>>(gcur, bstart, rowst, nbucket, cap, E, N);
  k_final<<<nbucket, 256, 0, stream>>>(tmp, gcur, bstart, rowst, csr, cap, N);
  k_prep<<<105, 256, 0, stream>>>(W1, b1, att1, W2, b2, att2, W1h, W2h, attB1, attB2, consts);

  int gblk = ((N+15)/16 + 3)/4;  // 4 waves/block, 16 nodes/wave
  k_gemm1<<<gblk, 256, 0, stream>>>(x, W1h, attB1, b1, consts, h1f8, a1i, a1j, N);
  k_agg1<<<(N*64+255)/256, 256, 0, stream>>>((const uint2*)h1f8, a1i, a1j, rowst, csr, bias1, (uint4*)x2h, N);

  k_gemm2<<<gblk, 256, 0, stream>>>(x2h, W2h, attB2, b2, consts, h2f8, a2i, a2j, N);
  k_agg2<<<(N+15)/16, 256, 0, stream>>>((const unsigned*)h2f8, a2i, a2j, rowst, csr, bias2, (float*)d_out, N);
}

// Round 4
// 303.252 us; speedup vs baseline: 1.5938x; 1.0403x over previous
//
#include <hip/hip_runtime.h>
#include <hip/hip_fp16.h>
#include <math.h>

// 2-layer GAT. f16 MFMA GEMMs (fused attention-scalar B-tiles, fused fp32->f16
// A-convert), fp8-e4m3 feature storage for the edge gathers, single-pass
// segment softmax, fp32 accumulation.
//
// CSR build (R13): two-level multi-split dodges the ~22G/s global-atomic wall
// (one device atomic per (block,bucket) ~300K instead of per-edge 1.6M).
// R15: split runs fused with gemm1 (independent work, one launch, block-range
// branch) so its time hides under GEMM compute; gcur zeroed by memset and
// split stores absolute base = b*cap + relative (k_initcur deleted).
//
// Aggregation: R14 deepened MLP (63us, VALUBusy 71% -> now VALU-issue-bound).
// R15 k_agg1 lane-remap: 8 lanes/edge x uint4 (16 fp8 ch/lane); with C1=16,
// lane o == head o exactly (one aj/ai/exp per lane-stage). 8 edges/stage at
// ~same instr count: VALU/edge -35%, VMEM instr/edge -50% (same bytes).
// Rings static-named (R11): cs/aj 8-deep (csr 64 ahead), features 4x uint4
// in flight (32 ahead).

typedef _Float16 f16x8 __attribute__((ext_vector_type(8)));   // 8 f16 (4 VGPRs)
typedef float f32x4 __attribute__((ext_vector_type(4)));
typedef float f32x2 __attribute__((ext_vector_type(2)));

__device__ __forceinline__ float lrelu02(float x){ return x > 0.f ? x : 0.2f*x; }
__device__ __forceinline__ unsigned char f2fp8(float v){
  return (unsigned char)(__builtin_amdgcn_cvt_pk_fp8_f32(v, v, 0, false) & 0xff);
}

#define BSHIFT 7                 // 128 nodes per bucket (N <= 131072)
#define BMASK  127
#define SPLIT_CHUNK 4096         // edges per split block

// ---------------- split body: bucket-group edges into tmp ----------------
__device__ __forceinline__ void split_body(int blk, const int* __restrict__ src,
    const int* __restrict__ dst, int* __restrict__ gcur, int* __restrict__ tmp,
    int E, int nbucket, int cap){
  __shared__ int hist[1024];
  int tid = threadIdx.x;
  for (int t = tid; t < 1024; t += 256) hist[t] = 0;
  __syncthreads();
  int lo = blk*SPLIT_CHUNK;
  int ds[16], ss[16];
  #pragma unroll
  for (int k = 0; k < 16; ++k){
    int i = lo + tid + k*256;
    bool p = i < E;
    ds[k] = p ? dst[i] : 0;
    ss[k] = p ? src[i] : 0;
    if (p) atomicAdd(&hist[ds[k] >> BSHIFT], 1);     // LDS atomic
  }
  __syncthreads();
  // one device atomic per nonzero bucket; hist[] becomes absolute base
  for (int b = tid; b < nbucket; b += 256){
    int c = hist[b];
    if (c) hist[b] = b*cap + atomicAdd(&gcur[b*16], c);
  }
  __syncthreads();
  #pragma unroll
  for (int k = 0; k < 16; ++k){
    int i = lo + tid + k*256;
    if (i < E){
      int r = atomicAdd(&hist[ds[k] >> BSHIFT], 1);  // LDS atomic, abs position
      tmp[r] = ss[k] | ((ds[k] & BMASK) << 17);
    }
  }
}

// ---------------- GEMM1 body (MFMA f16): h1 (fp8) + a1i/a1j ----------------
__device__ __forceinline__ void gemm1_body(int gb, const float* __restrict__ x,
    const _Float16* __restrict__ Wh, const _Float16* __restrict__ attB,
    const float* __restrict__ b1, const float* __restrict__ consts,
    unsigned char* __restrict__ h1f8, float* __restrict__ a1i, float* __restrict__ a1j, int N){
  int wid  = (gb*256 + (int)threadIdx.x) >> 6;
  int lane = threadIdx.x & 63;
  int m0 = wid*16;
  if (m0 >= N) return;
  int col = lane & 15, quad = lane >> 4;
  const float* xr = x + (size_t)(m0+col)*128 + quad*8;
  f32x4 acc[9];
  #pragma unroll
  for (int t=0;t<9;t++){ acc[t][0]=0.f; acc[t][1]=0.f; acc[t][2]=0.f; acc[t][3]=0.f; }
  #pragma unroll
  for (int q=0;q<4;q++){
    float4 f0 = ((const float4*)(xr + q*32))[0];
    float4 f1 = ((const float4*)(xr + q*32))[1];
    f16x8 a;
    a[0]=(_Float16)f0.x; a[1]=(_Float16)f0.y; a[2]=(_Float16)f0.z; a[3]=(_Float16)f0.w;
    a[4]=(_Float16)f1.x; a[5]=(_Float16)f1.y; a[6]=(_Float16)f1.z; a[7]=(_Float16)f1.w;
    #pragma unroll
    for (int t=0;t<8;t++){
      const f16x8* Bp = (const f16x8*)(Wh + (size_t)(t*16+col)*128 + q*32 + quad*8);
      acc[t] = __builtin_amdgcn_mfma_f32_16x16x32_f16(a, *Bp, acc[t], 0,0,0);
    }
    const f16x8* Ap = (const f16x8*)(attB + (size_t)col*128 + q*32 + quad*8);
    acc[8] = __builtin_amdgcn_mfma_f32_16x16x32_f16(a, *Ap, acc[8], 0,0,0);
  }
  #pragma unroll
  for (int t=0;t<8;t++){
    int c = t*16 + col;
    float bb = b1[c];
    #pragma unroll
    for (int r=0;r<4;r++){
      h1f8[(size_t)(m0 + quad*4 + r)*128 + c] = f2fp8(acc[t][r] + bb);
    }
  }
  float hb = consts[col];
  #pragma unroll
  for (int r=0;r<4;r++){
    int node = m0 + quad*4 + r;
    float v = acc[8][r] + hb;
    if (col < 8) a1i[node*8 + col] = v;
    else         a1j[node*8 + (col-8)] = v;
  }
}

// ---------------- fused: split (independent) || gemm1 ----------------
__global__ __launch_bounds__(256) void k_fused1(const int* __restrict__ src,
    const int* __restrict__ dst, int* __restrict__ gcur, int* __restrict__ tmp,
    int E, int nbucket, int nchunk, int cap,
    const float* __restrict__ x, const _Float16* __restrict__ Wh,
    const _Float16* __restrict__ attB, const float* __restrict__ b1,
    const float* __restrict__ consts, unsigned char* __restrict__ h1f8,
    float* __restrict__ a1i, float* __restrict__ a1j, int N){
  if ((int)blockIdx.x < nchunk)
    split_body(blockIdx.x, src, dst, gcur, tmp, E, nbucket, cap);
  else
    gemm1_body(blockIdx.x - nchunk, x, Wh, attB, b1, consts, h1f8, a1i, a1j, N);
}

// ---------------- bucket scan: counts -> bucketStart (exclusive) ----------------
__global__ void k_bscan(const int* __restrict__ gcur, int* __restrict__ bstart,
                        int* __restrict__ rowstart, int nbucket, int E, int N){
  __shared__ int lds[256];
  int t = threadIdx.x;
  int v[4]; int s = 0;
  #pragma unroll
  for (int k = 0; k < 4; ++k){
    int idx = t*4 + k;
    v[k] = (idx < nbucket) ? gcur[idx*16] : 0;
    s += v[k];
  }
  lds[t] = s;
  __syncthreads();
  for (int off = 1; off < 256; off <<= 1){
    int x = (t >= off) ? lds[t-off] : 0;
    __syncthreads();
    lds[t] += x;
    __syncthreads();
  }
  int run = (t == 0) ? 0 : lds[t-1];
  #pragma unroll
  for (int k = 0; k < 4; ++k){
    int idx = t*4 + k;
    if (idx < nbucket) bstart[idx] = run;
    run += v[k];
  }
  if (t == 0){ bstart[nbucket] = E; rowstart[N] = E; }
}

// ---------------- finalize: per-bucket node hist + scan -> rowstart + csr ----------------
__global__ __launch_bounds__(256) void k_final(const int* __restrict__ tmp,
    const int* __restrict__ gcur, const int* __restrict__ bstart,
    int* __restrict__ rowstart, int* __restrict__ csr, int cap, int N){
  __shared__ int h[128];
  __shared__ int sc[128];
  __shared__ int cur[128];
  int b = blockIdx.x;
  int tid = threadIdx.x;
  int cnt  = gcur[b*16];
  int base = bstart[b];
  if (tid < 128) h[tid] = 0;
  __syncthreads();
  const int* tb = tmp + (size_t)b*cap;
  for (int i = tid; i < cnt; i += 256) atomicAdd(&h[tb[i] >> 17], 1);
  __syncthreads();
  if (tid < 128) sc[tid] = h[tid];
  __syncthreads();
  for (int off = 1; off < 128; off <<= 1){
    int x = (tid < 128 && tid >= off) ? sc[tid-off] : 0;
    __syncthreads();
    if (tid < 128) sc[tid] += x;
    __syncthreads();
  }
  if (tid < 128){
    int excl = sc[tid] - h[tid];
    int node = b*128 + tid;
    if (node < N) rowstart[node] = base + excl;
    cur[tid] = base + excl;
  }
  __syncthreads();
  for (int i = tid; i < cnt; i += 256){
    int v = tb[i];
    int p = atomicAdd(&cur[v >> 17], 1);
    csr[p] = v & 0x1FFFF;
  }
}

// ---------------- weight prep: f16 weights + att-folded tiles + bias consts ----------------
__global__ void k_prep(const float* __restrict__ W1, const float* __restrict__ b1,
                       const float* __restrict__ att1,
                       const float* __restrict__ W2, const float* __restrict__ b2,
                       const float* __restrict__ att2,
                       _Float16* __restrict__ W1h, _Float16* __restrict__ W2h,
                       _Float16* __restrict__ attB1, _Float16* __restrict__ attB2,
                       float* __restrict__ consts){
  int i = blockIdx.x*blockDim.x + threadIdx.x;
  if (i < 16384){ W1h[i] = (_Float16)W1[i]; return; }
  i -= 16384;
  if (i < 6144){ int r = i >> 7; W2h[i] = (r < 40)? (_Float16)W2[i] : (_Float16)0.f; return; }
  i -= 6144;
  if (i < 2048){
    int j = i >> 7, k = i & 127;
    int h = j & 7, half = (j >> 3)*16;
    float s = 0.f;
    for (int c = 0; c < 16; ++c) s += att1[h*32 + half + c]*W1[(h*16+c)*128 + k];
    attB1[i] = (_Float16)s; return;
  }
  i -= 2048;
  if (i < 2048){
    int j = i >> 7, k = i & 127;
    float s = 0.f;
    if (j < 2){ const float* av = att2 + j*40; for (int c = 0; c < 40; ++c) s += av[c]*W2[c*128 + k]; }
    attB2[i] = (_Float16)s; return;
  }
  i -= 2048;
  if (i < 18){
    float s = 0.f;
    if (i < 8){ for (int c = 0; c < 16; ++c) s += b1[i*16+c]*att1[i*32+c]; }
    else if (i < 16){ int h = i-8; for (int c = 0; c < 16; ++c) s += b1[h*16+c]*att1[h*32+16+c]; }
    else if (i == 16){ for (int c = 0; c < 40; ++c) s += b2[c]*att2[c]; }
    else { for (int c = 0; c < 40; ++c) s += b2[c]*att2[40+c]; }
    consts[i] = s;
  }
}

// ---------------- layer-1 fused softmax+aggregate: 8 lanes/edge, uint4 fp8 ----------------
// one wave per node; octet oct = lane>>3 owns edge e+oct of each group of 8;
// lane o = lane&7 owns channels 16o..16o+15 (uint4 of fp8) == HEAD o exactly.
// cs/aj rings 8 deep (csr 64 edges ahead); feature ring u0..u3 (32 ahead).
__global__ __launch_bounds__(256) void k_agg1(const uint4* __restrict__ h1q4,
    const float* __restrict__ a1i, const float* __restrict__ a1j,
    const int* __restrict__ rowstart, const int* __restrict__ csr,
    const float* __restrict__ bias, uint4* __restrict__ x2u4, int N){
  int lane = threadIdx.x & 63;
  int n = (blockIdx.x*blockDim.x + threadIdx.x) >> 6;
  if (n >= N) return;
  int o = lane & 7, oct = lane >> 3;
  int rs = rowstart[n], re = rowstart[n+1];
  float ai2 = a1i[(unsigned)n*8u + (unsigned)o];
  float s0=0.f,s1=0.f,s2=0.f,s3=0.f,s4=0.f,s5=0.f,s6=0.f,s7=0.f;
  float s8=0.f,s9=0.f,s10=0.f,s11=0.f,s12=0.f,s13=0.f,s14=0.f,s15=0.f;
  float den=0.f;

#define ACC16(U, W)                                                          \
  { f32x2 g;                                                                 \
    g = __builtin_amdgcn_cvt_pk_f32_fp8((int)(U).x,false); s0 +=(W)*g[0]; s1 +=(W)*g[1]; \
    g = __builtin_amdgcn_cvt_pk_f32_fp8((int)(U).x,true ); s2 +=(W)*g[0]; s3 +=(W)*g[1]; \
    g = __builtin_amdgcn_cvt_pk_f32_fp8((int)(U).y,false); s4 +=(W)*g[0]; s5 +=(W)*g[1]; \
    g = __builtin_amdgcn_cvt_pk_f32_fp8((int)(U).y,true ); s6 +=(W)*g[0]; s7 +=(W)*g[1]; \
    g = __builtin_amdgcn_cvt_pk_f32_fp8((int)(U).z,false); s8 +=(W)*g[0]; s9 +=(W)*g[1]; \
    g = __builtin_amdgcn_cvt_pk_f32_fp8((int)(U).z,true ); s10+=(W)*g[0]; s11+=(W)*g[1]; \
    g = __builtin_amdgcn_cvt_pk_f32_fp8((int)(U).w,false); s12+=(W)*g[0]; s13+=(W)*g[1]; \
    g = __builtin_amdgcn_cvt_pk_f32_fp8((int)(U).w,true ); s14+=(W)*g[0]; s15+=(W)*g[1]; }

  { // self loop (always present; counted once via oct==0)
    float w = (oct==0)? __expf(lrelu02(ai2 + a1j[(unsigned)n*8u + (unsigned)o])) : 0.f;
    uint4 u = h1q4[(unsigned)n*8u + (unsigned)o];
    ACC16(u, w)
    den = w;
  }
  int last = re - 1;
  if (rs < re){
    unsigned cs0 = (unsigned)csr[min(rs+ 0+oct,last)];
    unsigned cs1 = (unsigned)csr[min(rs+ 8+oct,last)];
    unsigned cs2 = (unsigned)csr[min(rs+16+oct,last)];
    unsigned cs3 = (unsigned)csr[min(rs+24+oct,last)];
    unsigned cs4 = (unsigned)csr[min(rs+32+oct,last)];
    unsigned cs5 = (unsigned)csr[min(rs+40+oct,last)];
    unsigned cs6 = (unsigned)csr[min(rs+48+oct,last)];
    unsigned cs7 = (unsigned)csr[min(rs+56+oct,last)];
    float aj0 = a1j[cs0*8u+o], aj1 = a1j[cs1*8u+o];
    float aj2 = a1j[cs2*8u+o], aj3 = a1j[cs3*8u+o];
    float aj4 = a1j[cs4*8u+o], aj5 = a1j[cs5*8u+o];
    float aj6 = a1j[cs6*8u+o], aj7 = a1j[cs7*8u+o];
    uint4 u0 = h1q4[(size_t)cs0*8u + (unsigned)o];
    uint4 u1 = h1q4[(size_t)cs1*8u + (unsigned)o];
    uint4 u2 = h1q4[(size_t)cs2*8u + (unsigned)o];
    uint4 u3 = h1q4[(size_t)cs3*8u + (unsigned)o];
    int e0 = rs;

// stage: consume US (edge e0+OFF+oct), reissue US from CF (slot holding edge
// OFF+32), refresh CS/AJ with edge OFF+64.
#define AGG1_ST(US, CF, CS, AJ, OFF)                                         \
    {                                                                        \
      uint4 cur = US;                                                        \
      US = h1q4[(size_t)CF*8u + (unsigned)o];                                \
      unsigned nc = (unsigned)csr[min(e0+OFF+64+oct, last)];                 \
      float w = (e0+OFF+oct < re)? __expf(lrelu02(ai2 + AJ)) : 0.f;          \
      den += w;                                                              \
      ACC16(cur, w)                                                          \
      CS = nc; AJ = a1j[nc*8u + (unsigned)o];                                \
    }

    while (e0 < re){
      AGG1_ST(u0, cs4, cs0, aj0, 0)
      if (e0+8 >= re) break;
      AGG1_ST(u1, cs5, cs1, aj1, 8)
      if (e0+16 >= re) break;
      AGG1_ST(u2, cs6, cs2, aj2, 16)
      if (e0+24 >= re) break;
      AGG1_ST(u3, cs7, cs3, aj3, 24)
      if (e0+32 >= re) break;
      AGG1_ST(u0, cs0, cs4, aj4, 32)
      if (e0+40 >= re) break;
      AGG1_ST(u1, cs1, cs5, aj5, 40)
      if (e0+48 >= re) break;
      AGG1_ST(u2, cs2, cs6, aj6, 48)
      if (e0+56 >= re) break;
      AGG1_ST(u3, cs3, cs7, aj7, 56)
      e0 += 64;
    }
#undef AGG1_ST
  }
#undef ACC16
  #pragma unroll
  for (int off = 8; off < 64; off <<= 1){
    den += __shfl_xor(den, off);
    s0 += __shfl_xor(s0, off);  s1 += __shfl_xor(s1, off);
    s2 += __shfl_xor(s2, off);  s3 += __shfl_xor(s3, off);
    s4 += __shfl_xor(s4, off);  s5 += __shfl_xor(s5, off);
    s6 += __shfl_xor(s6, off);  s7 += __shfl_xor(s7, off);
    s8 += __shfl_xor(s8, off);  s9 += __shfl_xor(s9, off);
    s10+= __shfl_xor(s10,off);  s11+= __shfl_xor(s11,off);
    s12+= __shfl_xor(s12,off);  s13+= __shfl_xor(s13,off);
    s14+= __shfl_xor(s14,off);  s15+= __shfl_xor(s15,off);
  }
  if (oct == 0){
    float invd = 1.f/(den + 1e-16f);
    const float4* b4 = (const float4*)(bias + 16*o);
    float4 bb0 = b4[0], bb1 = b4[1], bb2 = b4[2], bb3 = b4[3];
    float o0 =s0 *invd+bb0.x, o1 =s1 *invd+bb0.y, o2 =s2 *invd+bb0.z, o3 =s3 *invd+bb0.w;
    float o4 =s4 *invd+bb1.x, o5 =s5 *invd+bb1.y, o6 =s6 *invd+bb1.z, o7 =s7 *invd+bb1.w;
    float o8 =s8 *invd+bb2.x, o9 =s9 *invd+bb2.y, o10=s10*invd+bb2.z, o11=s11*invd+bb2.w;
    float o12=s12*invd+bb3.x, o13=s13*invd+bb3.y, o14=s14*invd+bb3.z, o15=s15*invd+bb3.w;
    o0 =(o0 >0.f)?o0 :(__expf(o0 )-1.f); o1 =(o1 >0.f)?o1 :(__expf(o1 )-1.f);
    o2 =(o2 >0.f)?o2 :(__expf(o2 )-1.f); o3 =(o3 >0.f)?o3 :(__expf(o3 )-1.f);
    o4 =(o4 >0.f)?o4 :(__expf(o4 )-1.f); o5 =(o5 >0.f)?o5 :(__expf(o5 )-1.f);
    o6 =(o6 >0.f)?o6 :(__expf(o6 )-1.f); o7 =(o7 >0.f)?o7 :(__expf(o7 )-1.f);
    o8 =(o8 >0.f)?o8 :(__expf(o8 )-1.f); o9 =(o9 >0.f)?o9 :(__expf(o9 )-1.f);
    o10=(o10>0.f)?o10:(__expf(o10)-1.f); o11=(o11>0.f)?o11:(__expf(o11)-1.f);
    o12=(o12>0.f)?o12:(__expf(o12)-1.f); o13=(o13>0.f)?o13:(__expf(o13)-1.f);
    o14=(o14>0.f)?o14:(__expf(o14)-1.f); o15=(o15>0.f)?o15:(__expf(o15)-1.f);
    __half2 p0 = __floats2half2_rn(o0 ,o1 ), p1 = __floats2half2_rn(o2 ,o3 );
    __half2 p2 = __floats2half2_rn(o4 ,o5 ), p3 = __floats2half2_rn(o6 ,o7 );
    __half2 p4 = __floats2half2_rn(o8 ,o9 ), p5 = __floats2half2_rn(o10,o11);
    __half2 p6 = __floats2half2_rn(o12,o13), p7 = __floats2half2_rn(o14,o15);
    uint4 w0, w1;
    w0.x = *(unsigned*)&p0; w0.y = *(unsigned*)&p1; w0.z = *(unsigned*)&p2; w0.w = *(unsigned*)&p3;
    w1.x = *(unsigned*)&p4; w1.y = *(unsigned*)&p5; w1.z = *(unsigned*)&p6; w1.w = *(unsigned*)&p7;
    x2u4[(unsigned)n*16u + (unsigned)(o*2)    ] = w0;   // x2 stays f16 (MFMA A)
    x2u4[(unsigned)n*16u + (unsigned)(o*2 + 1)] = w1;
  }
}

// ---------------- GEMM2 (MFMA f16): h2 (fp8) + a2i/a2j ----------------
__global__ __launch_bounds__(256) void k_gemm2(const _Float16* __restrict__ xh,
    const _Float16* __restrict__ Wh, const _Float16* __restrict__ attB,
    const float* __restrict__ b2, const float* __restrict__ consts,
    unsigned char* __restrict__ h2f8, float* __restrict__ a2i, float* __restrict__ a2j, int N){
  int wid  = (blockIdx.x*256 + threadIdx.x) >> 6;
  int lane = threadIdx.x & 63;
  int m0 = wid*16;
  if (m0 >= N) return;
  int col = lane & 15, quad = lane >> 4;
  const f16x8* A8 = (const f16x8*)(xh + (size_t)(m0+col)*128 + quad*8);
  f32x4 acc[4];
  #pragma unroll
  for (int t=0;t<4;t++){ acc[t][0]=0.f; acc[t][1]=0.f; acc[t][2]=0.f; acc[t][3]=0.f; }
  #pragma unroll
  for (int q=0;q<4;q++){
    f16x8 a = A8[q*4];
    #pragma unroll
    for (int t=0;t<3;t++){
      const f16x8* Bp = (const f16x8*)(Wh + (size_t)(t*16+col)*128 + q*32 + quad*8);
      acc[t] = __builtin_amdgcn_mfma_f32_16x16x32_f16(a, *Bp, acc[t], 0,0,0);
    }
    const f16x8* Bp2 = (const f16x8*)(attB + (size_t)col*128 + q*32 + quad*8);
    acc[3] = __builtin_amdgcn_mfma_f32_16x16x32_f16(a, *Bp2, acc[3], 0,0,0);
  }
  #pragma unroll
  for (int t=0;t<3;t++){
    int c = t*16 + col;
    if (c < 40){
      float bb = b2[c];
      #pragma unroll
      for (int r=0;r<4;r++){
        h2f8[(size_t)(m0 + quad*4 + r)*40 + c] = f2fp8(acc[t][r] + bb);
      }
    }
  }
  if (col < 2){
    float cc = consts[16 + col];
    #pragma unroll
    for (int r=0;r<4;r++){
      int node = m0 + quad*4 + r;
      if (col == 0) a2i[node] = acc[3][r] + cc;
      else          a2j[node] = acc[3][r] + cc;
    }
  }
}

// ---------------- layer-2 fused softmax+aggregate + log_softmax ----------------
// FOUR nodes per wave (quarters); lanes ql<10 own 4 channels (uint of fp8).
// Per-quarter divergent edge loop, 8-stage pipeline: cs/aj rings 8 deep,
// feature ring 4 (issued 4 edges ahead). fp32 accumulation.
__global__ __launch_bounds__(256) void k_agg2(const unsigned* __restrict__ h2u,
    const float* __restrict__ a2i, const float* __restrict__ a2j,
    const int* __restrict__ rowstart, const int* __restrict__ csr,
    const float* __restrict__ bias, float* __restrict__ out, int N){
  int lane = threadIdx.x & 63;
  int wid = (blockIdx.x*blockDim.x + threadIdx.x) >> 6;
  int qt = lane >> 4, ql = lane & 15;
  int n = wid*4 + qt;
  if (n >= N) return;
  bool act = ql < 10;
  unsigned cl = act ? (unsigned)ql : 0u;
  int rs = rowstart[n], re = rowstart[n+1];
  float ai = a2i[n];
  float wself = __expf(lrelu02(ai + a2j[n]));
  float a0,a1,a2,a3,den;
  {
    unsigned u = h2u[(unsigned)n*10u + cl];
    f32x2 f0 = __builtin_amdgcn_cvt_pk_f32_fp8((int)u, false);
    f32x2 f1 = __builtin_amdgcn_cvt_pk_f32_fp8((int)u, true);
    a0 = wself*f0[0]; a1 = wself*f0[1]; a2 = wself*f1[0]; a3 = wself*f1[1];
    den = wself;
  }
  if (rs < re){
    int last = re - 1;
    unsigned cs0 = (unsigned)csr[min(rs+0,last)];
    unsigned cs1 = (unsigned)csr[min(rs+1,last)];
    unsigned cs2 = (unsigned)csr[min(rs+2,last)];
    unsigned cs3 = (unsigned)csr[min(rs+3,last)];
    unsigned cs4 = (unsigned)csr[min(rs+4,last)];
    unsigned cs5 = (unsigned)csr[min(rs+5,last)];
    unsigned cs6 = (unsigned)csr[min(rs+6,last)];
    unsigned cs7 = (unsigned)csr[min(rs+7,last)];
    float aj0 = a2j[cs0], aj1 = a2j[cs1], aj2 = a2j[cs2], aj3 = a2j[cs3];
    float aj4 = a2j[cs4], aj5 = a2j[cs5], aj6 = a2j[cs6], aj7 = a2j[cs7];
    unsigned u0 = h2u[cs0*10u + cl];
    unsigned u1 = h2u[cs1*10u + cl];
    unsigned u2 = h2u[cs2*10u + cl];
    unsigned u3 = h2u[cs3*10u + cl];
    int e0 = rs;

#define AGG2_ST(US, CF, CS, AJ, OFF)                                         \
    {                                                                        \
      unsigned cur = US;                                                     \
      US = h2u[CF*10u + cl];                                                 \
      unsigned nc = (unsigned)csr[min(e0+OFF+8, last)];                      \
      float w = (e0+OFF < re)? __expf(lrelu02(ai + AJ)) : 0.f;               \
      den += w;                                                              \
      f32x2 g0 = __builtin_amdgcn_cvt_pk_f32_fp8((int)cur, false);           \
      f32x2 g1 = __builtin_amdgcn_cvt_pk_f32_fp8((int)cur, true);            \
      a0 += w*g0[0]; a1 += w*g0[1]; a2 += w*g1[0]; a3 += w*g1[1];            \
      CS = nc; AJ = a2j[nc];                                                 \
    }

    while (e0 < re){
      AGG2_ST(u0, cs4, cs0, aj0, 0)
      AGG2_ST(u1, cs5, cs1, aj1, 1)
      AGG2_ST(u2, cs6, cs2, aj2, 2)
      AGG2_ST(u3, cs7, cs3, aj3, 3)
      AGG2_ST(u0, cs0, cs4, aj4, 4)
      AGG2_ST(u1, cs1, cs5, aj5, 5)
      AGG2_ST(u2, cs2, cs6, aj6, 6)
      AGG2_ST(u3, cs3, cs7, aj7, 7)
      e0 += 8;
    }
#undef AGG2_ST
  }
  float invd = 1.f/(den + 1e-16f);
  const float4* b4 = (const float4*)(bias + 4*cl);
  float4 bb = b4[0];
  float v0 = a0*invd + bb.x, v1 = a1*invd + bb.y;
  float v2 = a2*invd + bb.z, v3 = a3*invd + bb.w;
  float mv = act ? fmaxf(fmaxf(v0,v1), fmaxf(v2,v3)) : -INFINITY;
  #pragma unroll
  for (int off = 1; off < 16; off <<= 1) mv = fmaxf(mv, __shfl_xor(mv, off));
  float se = act ? (__expf(v0-mv)+__expf(v1-mv)+__expf(v2-mv)+__expf(v3-mv)) : 0.f;
  #pragma unroll
  for (int off = 1; off < 16; off <<= 1) se += __shfl_xor(se, off);
  float ls = __logf(se);
  if (act){
    float4 o = make_float4(v0-mv-ls, v1-mv-ls, v2-mv-ls, v3-mv-ls);
    ((float4*)out)[(unsigned)n*10u + cl] = o;
  }
}

extern "C" void kernel_launch(void* const* d_in, const int* in_sizes, int n_in,
                              void* d_out, int out_size, void* d_ws, size_t ws_size,
                              hipStream_t stream){
  const float* x     = (const float*)d_in[0];
  const int*   ei    = (const int*)  d_in[1];
  const float* W1    = (const float*)d_in[2];
  const float* b1    = (const float*)d_in[3];
  const float* att1  = (const float*)d_in[4];
  const float* bias1 = (const float*)d_in[5];
  const float* W2    = (const float*)d_in[6];
  const float* b2    = (const float*)d_in[7];
  const float* att2  = (const float*)d_in[8];
  const float* bias2 = (const float*)d_in[9];
  int N = in_sizes[0] / 128;
  int E = in_sizes[1] / 2;
  const int* src = ei;
  const int* dst = ei + E;

  char* ws = (char*)d_ws;
  size_t off = 0;
  auto alloc = [&](size_t bytes)->char*{
    char* p = ws + off; off += (bytes + 255) & ~(size_t)255; return p;
  };
  unsigned char* h1f8 = (unsigned char*)alloc((size_t)N*128);   // fp8 row-major
  _Float16*      x2h  = (_Float16*)alloc((size_t)N*128*2);      // f16 (MFMA A)
  unsigned char* h2f8 = (unsigned char*)alloc((size_t)N*40);    // fp8 row-major
  float* a1i  = (float*)alloc((size_t)N*8*4);
  float* a1j  = (float*)alloc((size_t)N*8*4);
  float* a2i  = (float*)alloc((size_t)N*4);
  float* a2j  = (float*)alloc((size_t)N*4);
  _Float16* W1h   = (_Float16*)alloc(16384*2);
  _Float16* W2h   = (_Float16*)alloc(6144*2);
  _Float16* attB1 = (_Float16*)alloc(2048*2);
  _Float16* attB2 = (_Float16*)alloc(2048*2);
  float* consts = (float*)alloc(18*4);
  int*   rowst = (int*)  alloc((size_t)(N+1)*4);
  int*   csr   = (int*)  alloc((size_t)E*4);

  int nbucket = (N + BMASK) >> BSHIFT;           // <= 1024 for N <= 131072
  int meanb = (E + nbucket - 1)/nbucket;
  int cap = ((2*meanb + 1023)/1024)*1024;        // ~2x mean: +dozens of sigma
  if (cap < 2048) cap = 2048;

  int*   gcur   = (int*)alloc((size_t)nbucket*64);   // 1 counter per 64B line
  int*   bstart = (int*)alloc((size_t)(nbucket+1)*4);
  int*   tmp    = (int*)x2h;                         // alias: dead until k_agg1

  int nchunk = (E + SPLIT_CHUNK - 1)/SPLIT_CHUNK;
  int gblk = ((N+15)/16 + 3)/4;  // 4 waves/block, 16 nodes/wave

  hipMemsetAsync(gcur, 0, (size_t)nbucket*64, stream);
  k_prep<<<105, 256, 0, stream>>>(W1, b1, att1, W2, b2, att2, W1h, W2h, attB1, attB2, consts);
  k_fused1<<<nchunk + gblk, 256, 0, stream>>>(src, dst, gcur, tmp, E, nbucket, nchunk, cap,
                                              x, W1h, attB1, b1, consts, h1f8, a1i, a1j, N);
  k_bscan<<<1, 256, 0, stream>>>(gcur, bstart, rowst, nbucket, E, N);
  k_final<<<nbucket, 256, 0, stream>>>(tmp, gcur, bstart, rowst, csr, cap, N);

  k_agg1<<<(N*64+255)/256, 256, 0, stream>>>((const uint4*)h1f8, a1i, a1j, rowst, csr, bias1, (uint4*)x2h, N);

  k_gemm2<<<gblk, 256, 0, stream>>>(x2h, W2h, attB2, b2, consts, h2f8, a2i, a2j, N);
  k_agg2<<<(N+15)/16, 256, 0, stream>>>((const unsigned*)h2f8, a2i, a2j, rowst, csr, bias2, (float*)d_out, N);
}